// Round 7
// baseline (3595.753 us; speedup 1.0000x reference)
//
#include <hip/hip_runtime.h>

typedef __bf16 bf16;
typedef bf16 bf16x8 __attribute__((ext_vector_type(8)));
typedef float f32x4 __attribute__((ext_vector_type(4)));
typedef _Float16 f16;
typedef f16 f16x8 __attribute__((ext_vector_type(8)));

#define NBT 4096      // B*T = 8*512
#define NJ 21
#define NLF 86016     // NBT*NJ
#define DD 256
#define CONV_M 86352  // 168*514
#define SPAD 514
#define CROWS 86528   // 1 guard row + 86352 + overrun slack

// flags: 1=A_F32  2=OUT_F32(C32)  4=RELU  8=BNSS(sc/sh)  16=PADZ(conv layout)
//        32=LFOUT(remap conv row -> lf row)  64=XWT(+bias, remap bt->t*8+b, f32)
__global__ __launch_bounds__(256, 2) void gemm_bf16(
    const void* __restrict__ Av, const bf16* __restrict__ Bt,
    float* __restrict__ C32, bf16* __restrict__ Cout,
    const float* __restrict__ bias, const float* __restrict__ sc,
    const float* __restrict__ sh, int M, int N, int K, int lda, int flags)
{
  __shared__ bf16 As[128][40];
  __shared__ bf16 Bs[128][40];
  const int tid = threadIdx.x;
  const long m0 = (long)blockIdx.y * 128;
  const int n0 = blockIdx.x * 128;
  const int wave = tid >> 6, lane = tid & 63;
  const int wm = (wave & 1) * 64, wn = (wave >> 1) * 64;
  const int lr = tid >> 1, lc = (tid & 1) * 16;
  const int frow = lane & 15, fkb = (lane >> 4) * 8;
  f32x4 acc[4][4] = {};
  for (int k0 = 0; k0 < K; k0 += 32) {
    if (flags & 1) {
      const float* ap = (const float*)Av + (m0 + lr) * (long)lda + (k0 + lc);
      bf16x8 t0, t1;
      #pragma unroll
      for (int u = 0; u < 8; u++) { t0[u] = (bf16)ap[u]; t1[u] = (bf16)ap[8 + u]; }
      *(bf16x8*)(&As[lr][lc])     = t0;
      *(bf16x8*)(&As[lr][lc + 8]) = t1;
    } else {
      const bf16* ap = (const bf16*)Av + (m0 + lr) * (long)lda + (k0 + lc);
      *(bf16x8*)(&As[lr][lc])     = *(const bf16x8*)(ap);
      *(bf16x8*)(&As[lr][lc + 8]) = *(const bf16x8*)(ap + 8);
    }
    const bf16* bp = Bt + (n0 + lr) * (long)K + (k0 + lc);
    *(bf16x8*)(&Bs[lr][lc])     = *(const bf16x8*)(bp);
    *(bf16x8*)(&Bs[lr][lc + 8]) = *(const bf16x8*)(bp + 8);
    __syncthreads();
    bf16x8 af[4], bg[4];
    #pragma unroll
    for (int i = 0; i < 4; i++) af[i] = *(const bf16x8*)(&As[wm + i * 16 + frow][fkb]);
    #pragma unroll
    for (int j = 0; j < 4; j++) bg[j] = *(const bf16x8*)(&Bs[wn + j * 16 + frow][fkb]);
    #pragma unroll
    for (int i = 0; i < 4; i++)
      #pragma unroll
      for (int j = 0; j < 4; j++)
        acc[i][j] = __builtin_amdgcn_mfma_f32_16x16x32_bf16(af[i], bg[j], acc[i][j], 0, 0, 0);
    __syncthreads();
  }
  const int col = lane & 15, rbase = (lane >> 4) * 4;
  #pragma unroll
  for (int i = 0; i < 4; i++) {
    #pragma unroll
    for (int j = 0; j < 4; j++) {
      const int nn = n0 + wn + j * 16 + col;
      #pragma unroll
      for (int r = 0; r < 4; r++) {
        const long mm = m0 + wm + i * 16 + rbase + r;
        if (mm >= M) continue;
        float v = acc[i][j][r];
        if (flags & 64) {            // xw for LSTM: +bias, remap row bt -> t*8+b
          float vv = v; if (bias) vv += bias[nn];
          const long dr = ((mm & 511) << 3) + (mm >> 9);
          C32[dr * (long)N + nn] = vv;
          continue;
        }
        if (flags & 2) { C32[mm * (long)N + nn] = v; continue; }
        if (flags & 8) v = v * sc[nn] + sh[nn];
        else if (bias) v += bias[nn];
        if (flags & 4) v = fmaxf(v, 0.f);
        if (flags & 16) {
          const int s = (int)(mm % SPAD);
          if (s == 0 || s == SPAD - 1) v = 0.f;
          Cout[mm * (long)N + nn] = (bf16)v;
        } else if (flags & 32) {
          const long hj = mm / SPAD; const int s = (int)(mm - hj * SPAD);
          if (s == 0 || s == SPAD - 1) continue;
          const long b = hj / NJ; const int j2 = (int)(hj - b * NJ);
          const long dst = (b * 512 + (s - 1)) * NJ + j2;
          Cout[dst * (long)N + nn] = (bf16)v;
        } else {
          Cout[mm * (long)N + nn] = (bf16)v;
        }
      }
    }
  }
}

// ---------------- weight prep (f32 -> bf16) ----------------
__global__ void cvt_k(const float* __restrict__ s, bf16* __restrict__ d, long n) {
  long i = (long)blockIdx.x * 256 + threadIdx.x;
  if (i < n) d[i] = (bf16)s[i];
}
__global__ void prep_gatW(const float* __restrict__ W, bf16* __restrict__ Wt, int F) {
  long idx = (long)blockIdx.x * 256 + threadIdx.x;   // 256*F
  if (idx >= 256L * F) return;
  int n = (int)(idx / F), f = (int)(idx % F);
  Wt[idx] = (bf16)W[((long)(n >> 6) * F + f) * 64 + (n & 63)];
}
__global__ void prep_convw(const float* __restrict__ w, bf16* __restrict__ wp) {
  int idx = blockIdx.x * 256 + threadIdx.x;          // 256*768
  int n = idx / 768, k = idx % 768, tap = k >> 8, i = k & 255;
  wp[idx] = (bf16)w[(n * 256 + i) * 3 + tap];
}
__global__ void prep_out2(const float* __restrict__ w, bf16* __restrict__ wp) {
  int idx = blockIdx.x * 256 + threadIdx.x;          // 128*256
  wp[idx] = (idx < 63 * 256) ? (bf16)w[idx] : (bf16)0.f;
}
__global__ void prep_scsh(const float* __restrict__ cb, const float* __restrict__ g,
                          const float* __restrict__ be, const float* __restrict__ m,
                          const float* __restrict__ v, float* __restrict__ sc,
                          float* __restrict__ sh) {
  int c = threadIdx.x;
  float rs = rsqrtf(v[c] + 1e-5f) * g[c];
  sc[c] = rs; sh[c] = (cb[c] - m[c]) * rs + be[c];
}
__global__ void prep_lb(const float* __restrict__ bihF, const float* __restrict__ bhhF,
                        const float* __restrict__ bihB, const float* __restrict__ bhhB,
                        float* __restrict__ o) {
  int n = blockIdx.x * 256 + threadIdx.x;            // 1024
  if (n >= 1024) return;
  o[n] = (n < 512) ? (bihF[n] + bhhF[n]) : (bihB[n - 512] + bhhB[n - 512]);
}
__global__ void pad_zero(bf16* __restrict__ convIn) {
  int idx = blockIdx.x * 256 + threadIdx.x;          // 168*2*256
  int hj = idx >> 9, s = ((idx >> 8) & 1) ? (SPAD - 1) : 0, c = idx & 255;
  convIn[((long)hj * SPAD + s) * DD + c] = (bf16)0.f;
}
__global__ void zero_out(float* __restrict__ o, long n) {
  long i = (long)blockIdx.x * 256 + threadIdx.x;
  if (i < n) o[i] = 0.f;
}

// ---------------- GAT attention (per bt block; in-place safe) ----------------
__global__ __launch_bounds__(256) void gat_attn(
    const bf16* __restrict__ Wh, const float* __restrict__ a,
    const float* __restrict__ adj, bf16* __restrict__ out, int convMode)
{
  const int bt = blockIdx.x, tid = threadIdx.x;
  __shared__ float whs[NJ][DD];
  __shared__ float s1[4][NJ], s2[4][NJ];
  __shared__ float att[4][NJ][NJ];
  const long base = (long)bt * NJ * DD;
  for (int i = tid; i < NJ * DD; i += 256)
    whs[i >> 8][i & 255] = (float)Wh[base + i];
  __syncthreads();
  if (tid < 4 * NJ) {
    const int h = tid / NJ, i = tid % NJ;
    float x1 = 0.f, x2 = 0.f;
    for (int d = 0; d < 64; d++) {
      const float w = whs[i][h * 64 + d];
      x1 += w * a[h * 128 + d];
      x2 += w * a[h * 128 + 64 + d];
    }
    s1[h][i] = x1; s2[h][i] = x2;
  }
  __syncthreads();
  for (int idx = tid; idx < 4 * NJ * NJ; idx += 256) {
    const int h = idx / (NJ * NJ), r = idx % (NJ * NJ), i = r / NJ, j = r % NJ;
    float e = s1[h][i] + s2[h][j];
    e = e > 0.f ? e : 0.2f * e;
    att[h][i][j] = (adj[i * NJ + j] > 0.f) ? e : -9e15f;
  }
  __syncthreads();
  if (tid < 4 * NJ) {
    const int h = tid / NJ, i = tid % NJ;
    float mx = -3e38f;
    for (int j = 0; j < NJ; j++) mx = fmaxf(mx, att[h][i][j]);
    float sum = 0.f;
    for (int j = 0; j < NJ; j++) { const float ex = __expf(att[h][i][j] - mx); att[h][i][j] = ex; sum += ex; }
    const float inv = 1.f / sum;
    for (int j = 0; j < NJ; j++) att[h][i][j] *= inv;
  }
  __syncthreads();
  const int b = bt >> 9, t = bt & 511;
  for (int idx = tid; idx < NJ * DD; idx += 256) {
    const int i = idx >> 8, c = idx & 255, h = c >> 6;
    float s = 0.f;
    for (int j = 0; j < NJ; j++) s += att[h][i][j] * whs[j][c];
    s = s > 0.f ? s : (__expf(s) - 1.f);              // ELU
    const long row = convMode ? (((long)(b * NJ + i)) * SPAD + (t + 1)) : ((long)bt * NJ + i);
    out[row * DD + c] = (bf16)s;
  }
}

// ---------------- MHA core (per bt block; O may alias Q) ----------------
__global__ __launch_bounds__(256) void mha_core(
    const bf16* __restrict__ Q, const bf16* __restrict__ K,
    const bf16* __restrict__ V, bf16* __restrict__ O)
{
  const int bt = blockIdx.x, tid = threadIdx.x;
  __shared__ bf16 qs[NJ][DD], ks[NJ][DD], vs[NJ][DD];
  __shared__ float att[4][NJ][NJ];
  const long base = (long)bt * NJ * DD;
  for (int i = tid; i < NJ * DD; i += 256) {
    const int r = i >> 8, c = i & 255;
    qs[r][c] = Q[base + i]; ks[r][c] = K[base + i]; vs[r][c] = V[base + i];
  }
  __syncthreads();
  for (int idx = tid; idx < 4 * NJ * NJ; idx += 256) {
    const int h = idx / (NJ * NJ), r = idx % (NJ * NJ), i = r / NJ, j = r % NJ;
    float s = 0.f;
    for (int d = 0; d < 64; d++) s += (float)qs[i][h * 64 + d] * (float)ks[j][h * 64 + d];
    att[h][i][j] = s * 0.125f;
  }
  __syncthreads();
  if (tid < 4 * NJ) {
    const int h = tid / NJ, i = tid % NJ;
    float mx = -3e38f;
    for (int j = 0; j < NJ; j++) mx = fmaxf(mx, att[h][i][j]);
    float sum = 0.f;
    for (int j = 0; j < NJ; j++) { const float ex = __expf(att[h][i][j] - mx); att[h][i][j] = ex; sum += ex; }
    const float inv = 1.f / sum;
    for (int j = 0; j < NJ; j++) att[h][i][j] *= inv;
  }
  __syncthreads();
  for (int idx = tid; idx < NJ * DD; idx += 256) {
    const int i = idx >> 8, c = idx & 255, h = c >> 6;
    float s = 0.f;
    for (int j = 0; j < NJ; j++) s += att[h][i][j] * (float)vs[j][c];
    O[base + i * DD + c] = (bf16)s;
  }
}

// ---------------- residual + joint-mean pool ----------------
__global__ __launch_bounds__(256) void pool_kernel(
    const bf16* __restrict__ lf, const bf16* __restrict__ ao, bf16* __restrict__ o)
{
  const int bt = blockIdx.x, c = threadIdx.x;
  float s = 0.f;
  for (int j = 0; j < NJ; j++) {
    const long r = ((long)bt * NJ + j) * DD + c;
    s += (float)lf[r] + 0.5f * (float)ao[r];
  }
  o[(long)bt * DD + c] = (bf16)(s * (1.f / 21.f));
}

// ---------------- MFMA-batched persistent LSTM ----------------
// R6 post-mortem: __syncthreads drains vmcnt(0) -> the per-step xw prefetch
// and h stores stalled ~1000-2000cyc/step at the barriers. Fix: raw s_barrier
// with targeted lgkmcnt(0) waits only (loads/stores stay in flight), MFMAs
// interleaved across accumulators, h_lds stride 132 (4-way, was 8-way).
#define REP16(X) X(0) X(1) X(2) X(3) X(4) X(5) X(6) X(7) X(8) X(9) X(10) X(11) \
  X(12) X(13) X(14) X(15)

#define MFMA16(ACC, A, B) \
  asm volatile("v_mfma_f32_16x16x32_f16 %0, %1, %2, %0" : "+v"(ACC) : "v"(A), "a"(B))

#define LDS_FENCE() do { \
  asm volatile("s_waitcnt lgkmcnt(0)" ::: "memory"); \
  __builtin_amdgcn_sched_barrier(0); \
  __builtin_amdgcn_s_barrier(); \
  __builtin_amdgcn_sched_barrier(0); \
} while (0)

__global__ __launch_bounds__(512, 1) void lstm_mfma(
    const float* __restrict__ xwT,
    const float* __restrict__ whhF, const float* __restrict__ whhB,
    bf16* __restrict__ outL, bf16* __restrict__ outR)
{
  const int wg = blockIdx.x;                    // 0..3
  const int hand = wg >> 1, dir = wg & 1;
  const int tid = threadIdx.x;
  const int lane = tid & 63, w = tid >> 6;
  const int fcol = lane & 15, fq = lane >> 4;   // fq 0..3
  const bool actv = fq < 2;                     // C rows 0..7 = real batches
  const int nb = (w << 6) + fcol;               // gate column base
  const float* whh = dir ? whhB : whhF;

  __shared__ f16 h_lds[16][132];                // stride 264B -> 4-way max
  __shared__ float gs[8][520];

  // B-frags: elem i = whh[n = nb+16*nt][k = kt*32 + fq*8 + i]
  auto BL = [&](int nt, int kt) -> f16x8 {
    const float* p = whh + ((long)(nb + (nt << 4)) * 128 + (kt << 5) + (fq << 3));
    const f32x4 lo = *(const f32x4*)p, hi = *(const f32x4*)(p + 4);
    f16x8 r;
    r[0]=(f16)lo[0]; r[1]=(f16)lo[1]; r[2]=(f16)lo[2]; r[3]=(f16)lo[3];
    r[4]=(f16)hi[0]; r[5]=(f16)hi[1]; r[6]=(f16)hi[2]; r[7]=(f16)hi[3];
    return r;
  };
  f16x8 b00=BL(0,0), b01=BL(0,1), b02=BL(0,2), b03=BL(0,3);
  f16x8 b10=BL(1,0), b11=BL(1,1), b12=BL(1,2), b13=BL(1,3);
  f16x8 b20=BL(2,0), b21=BL(2,1), b22=BL(2,2), b23=BL(2,3);
  f16x8 b30=BL(3,0), b31=BL(3,1), b32=BL(3,2), b33=BL(3,3);
  asm volatile("" : "+a"(b00), "+a"(b01), "+a"(b02), "+a"(b03));
  asm volatile("" : "+a"(b10), "+a"(b11), "+a"(b12), "+a"(b13));
  asm volatile("" : "+a"(b20), "+a"(b21), "+a"(b22), "+a"(b23));
  asm volatile("" : "+a"(b30), "+a"(b31), "+a"(b32), "+a"(b33));

  // zero h state (rows 8..15 stay zero forever)
  {
    f16* hz = &h_lds[0][0];
    for (int i = tid; i < 16 * 132; i += 512) hz[i] = (f16)0.f;
  }
  float c0 = 0.f, c1 = 0.f;                     // cell state (gate phase)
  const float* xwp = xwT + ((long)(hand * 2 + dir) << 21);  // slot: t*8+b rows
  bf16* outp = (hand ? outR : outL) + (dir << 7);

  // prologue xw load (step 0)
  const int t0 = dir ? 511 : 0;
  const float* xq0 = xwp + (long)t0 * 4096;
#define XDECL(i) float xc##i = actv ? xq0[(((fq << 2) + ((i) & 3)) << 9) + nb + (((i) >> 2) << 4)] : 0.f; float xn##i;
  REP16(XDECL)
#undef XDECL
  __syncthreads();

  for (int s = 0; s < 512; s++) {
    const int tt = dir ? 511 - s : s;
    // A-frags: h[row = fcol][k = fq*8 + kt*32 + i]
    const f16* hr = &h_lds[fcol][fq << 3];
    f16x8 a0 = *(const f16x8*)(hr);
    f16x8 a1 = *(const f16x8*)(hr + 32);
    f16x8 a2 = *(const f16x8*)(hr + 64);
    f16x8 a3 = *(const f16x8*)(hr + 96);
    f32x4 acc0 = {xc0,  xc1,  xc2,  xc3};
    f32x4 acc1 = {xc4,  xc5,  xc6,  xc7};
    f32x4 acc2 = {xc8,  xc9,  xc10, xc11};
    f32x4 acc3 = {xc12, xc13, xc14, xc15};
    {   // prefetch next step's xw (stays in flight across raw barriers)
      int tn = dir ? 510 - s : s + 1;
      tn = tn < 0 ? 0 : (tn > 511 ? 511 : tn);
      const float* xq = xwp + (long)tn * 4096;
#define XLOAD(i) xn##i = actv ? xq[(((fq << 2) + ((i) & 3)) << 9) + nb + (((i) >> 2) << 4)] : 0.f;
      REP16(XLOAD)
#undef XLOAD
    }
    // interleaved across accumulators: consecutive MFMAs independent
    MFMA16(acc0, a0, b00); MFMA16(acc1, a0, b10); MFMA16(acc2, a0, b20); MFMA16(acc3, a0, b30);
    MFMA16(acc0, a1, b01); MFMA16(acc1, a1, b11); MFMA16(acc2, a1, b21); MFMA16(acc3, a1, b31);
    MFMA16(acc0, a2, b02); MFMA16(acc1, a2, b12); MFMA16(acc2, a2, b22); MFMA16(acc3, a2, b32);
    MFMA16(acc0, a3, b03); MFMA16(acc1, a3, b13); MFMA16(acc2, a3, b23); MFMA16(acc3, a3, b33);
    asm volatile("s_nop 7\n\ts_nop 7");          // MFMA->VALU/DS read hazard
    if (actv) {
      const int br = fq << 2;
      gs[br + 0][nb]      = acc0[0]; gs[br + 1][nb]      = acc0[1];
      gs[br + 2][nb]      = acc0[2]; gs[br + 3][nb]      = acc0[3];
      gs[br + 0][nb + 16] = acc1[0]; gs[br + 1][nb + 16] = acc1[1];
      gs[br + 2][nb + 16] = acc1[2]; gs[br + 3][nb + 16] = acc1[3];
      gs[br + 0][nb + 32] = acc2[0]; gs[br + 1][nb + 32] = acc2[1];
      gs[br + 2][nb + 32] = acc2[2]; gs[br + 3][nb + 32] = acc2[3];
      gs[br + 0][nb + 48] = acc3[0]; gs[br + 1][nb + 48] = acc3[1];
      gs[br + 2][nb + 48] = acc3[2]; gs[br + 3][nb + 48] = acc3[3];
    }
    LDS_FENCE();                                 // gs visible; vm stays in flight
    {   // gate phase: thread handles (bq, k) and (bq+4, k)
      const int k = tid & 127, bq = tid >> 7;
      {
        const float gi = gs[bq][k],       gf = gs[bq][128 + k];
        const float gg = gs[bq][256 + k], go = gs[bq][384 + k];
        const float si = __builtin_amdgcn_rcpf(1.f + __expf(-gi));
        const float sf = __builtin_amdgcn_rcpf(1.f + __expf(-gf));
        const float so = __builtin_amdgcn_rcpf(1.f + __expf(-go));
        const float tg = 1.f - 2.f * __builtin_amdgcn_rcpf(1.f + __expf(2.f * gg));
        c0 = sf * c0 + si * tg;
        const float tc = 1.f - 2.f * __builtin_amdgcn_rcpf(1.f + __expf(2.f * c0));
        const float h = so * tc;
        h_lds[bq][k] = (f16)h;
        outp[((long)bq * 512 + tt) * 256 + k] = (bf16)h;
      }
      {
        const int b = bq + 4;
        const float gi = gs[b][k],       gf = gs[b][128 + k];
        const float gg = gs[b][256 + k], go = gs[b][384 + k];
        const float si = __builtin_amdgcn_rcpf(1.f + __expf(-gi));
        const float sf = __builtin_amdgcn_rcpf(1.f + __expf(-gf));
        const float so = __builtin_amdgcn_rcpf(1.f + __expf(-go));
        const float tg = 1.f - 2.f * __builtin_amdgcn_rcpf(1.f + __expf(2.f * gg));
        c1 = sf * c1 + si * tg;
        const float tc = 1.f - 2.f * __builtin_amdgcn_rcpf(1.f + __expf(2.f * c1));
        const float h = so * tc;
        h_lds[b][k] = (f16)h;
        outp[((long)b * 512 + tt) * 256 + k] = (bf16)h;
      }
    }
    LDS_FENCE();                                 // new h visible
#define XSWAP(i) xc##i = xn##i;
    REP16(XSWAP)
#undef XSWAP
  }
}

// ---------------- final: +bias, *visibility ----------------
__global__ __launch_bounds__(256) void finalize_k(
    const float* __restrict__ y, const float* __restrict__ b2,
    const float* __restrict__ vis, float* __restrict__ out)
{
  const int idx = blockIdx.x * 256 + threadIdx.x;
  if (idx >= NBT * 63) return;
  const int c = idx % 63; const int bt = idx / 63;
  out[idx] = (y[(long)bt * 128 + c] + b2[c]) * vis[bt * 21 + (c / 3)];
}

extern "C" void kernel_launch(void* const* d_in, const int* in_sizes, int n_in,
                              void* d_out, int out_size, void* d_ws, size_t ws_size,
                              hipStream_t stream) {
  (void)in_sizes; (void)n_in;
  const float* feats[2] = { (const float*)d_in[0], (const float*)d_in[1] };
  const float* adj  = (const float*)d_in[2];
  const float* vis  = (const float*)d_in[3];
  const float* gW[2] = { (const float*)d_in[4], (const float*)d_in[6] };
  const float* ga[2] = { (const float*)d_in[5], (const float*)d_in[7] };
  const float* cw_[2] = { (const float*)d_in[8],  (const float*)d_in[10] };
  const float* cb_[2] = { (const float*)d_in[9],  (const float*)d_in[11] };
  const float* bng[2] = { (const float*)d_in[12], (const float*)d_in[16] };
  const float* bnb[2] = { (const float*)d_in[13], (const float*)d_in[17] };
  const float* bnm[2] = { (const float*)d_in[14], (const float*)d_in[18] };
  const float* bnv[2] = { (const float*)d_in[15], (const float*)d_in[19] };
  const float* wq = (const float*)d_in[20], *wk = (const float*)d_in[21];
  const float* wv = (const float*)d_in[22], *wo = (const float*)d_in[23];
  const float* bq = (const float*)d_in[24], *bk = (const float*)d_in[25];
  const float* bv = (const float*)d_in[26], *bo = (const float*)d_in[27];
  const float* Lwih[2][2] = { { (const float*)d_in[28], (const float*)d_in[32] },
                              { (const float*)d_in[36], (const float*)d_in[40] } };
  const float* Lwhh[2][2] = { { (const float*)d_in[29], (const float*)d_in[33] },
                              { (const float*)d_in[37], (const float*)d_in[41] } };
  const float* Lbih[2][2] = { { (const float*)d_in[30], (const float*)d_in[34] },
                              { (const float*)d_in[38], (const float*)d_in[42] } };
  const float* Lbhh[2][2] = { { (const float*)d_in[31], (const float*)d_in[35] },
                              { (const float*)d_in[39], (const float*)d_in[43] } };
  const float* o1w = (const float*)d_in[44], *o1b = (const float*)d_in[45];
  const float* o2w = (const float*)d_in[46], *o2b = (const float*)d_in[47];

  char* base = (char*)d_ws;
  size_t off = 0;
  auto alloc = [&](size_t b) { size_t r = off; off += (b + 1023) & ~(size_t)1023; return r; };
  const size_t SZ_LF  = (size_t)NLF * DD * 2;     // 44.04 MB
  const size_t SZ_CNV = (size_t)CROWS * DD * 2;   // 44.30 MB
  const size_t SZ_BT  = (size_t)NBT * DD * 2;     // 2.10 MB
  const size_t o_w1t = alloc((size_t)256 * 512 * 2);
  const size_t o_w2t = alloc((size_t)256 * 256 * 2);
  const size_t o_cw1 = alloc((size_t)256 * 768 * 2);
  const size_t o_cw2 = alloc((size_t)256 * 768 * 2);
  const size_t o_wq  = alloc((size_t)256 * 256 * 2);
  const size_t o_wk  = alloc((size_t)256 * 256 * 2);
  const size_t o_wv  = alloc((size_t)256 * 256 * 2);
  const size_t o_wo  = alloc((size_t)256 * 256 * 2);
  const size_t o_o1w = alloc((size_t)256 * 256 * 2);
  const size_t o_o2p = alloc((size_t)128 * 256 * 2);
  const size_t o_lw0 = alloc((size_t)512 * 256 * 2);
  const size_t o_lw1 = alloc((size_t)512 * 256 * 2);
  const size_t o_lw2 = alloc((size_t)512 * 256 * 2);
  const size_t o_lw3 = alloc((size_t)512 * 256 * 2);
  const size_t o_ss  = alloc((size_t)4 * 256 * 4);
  const size_t o_lb  = alloc((size_t)2048 * 4);   // lstm bias sums (2 layers x 2 dirs x 512)
  const size_t o_B1  = alloc(SZ_LF);
  const size_t o_B2  = alloc(SZ_CNV);
  const size_t o_B3  = alloc(SZ_CNV);
  const size_t o_lfL = alloc(SZ_LF);
  const size_t o_lfR = alloc(SZ_LF);
  const size_t o_le  = alloc(SZ_BT);
  const size_t o_re  = alloc(SZ_BT);
  const size_t o_h1L = alloc(SZ_BT);
  const size_t o_h1R = alloc(SZ_BT);
  const size_t o_hoL = alloc(SZ_BT);
  const size_t o_hoR = alloc(SZ_BT);
  const size_t o_t1  = alloc(SZ_BT);
  const size_t o_y32 = alloc((size_t)NBT * 128 * 4);
  const size_t NEED = off;
  if (ws_size < NEED) {   // graceful diagnostic: zero output, clean absmax-fail
    zero_out<<<(out_size + 255) / 256, 256, 0, stream>>>((float*)d_out, out_size);
    return;
  }
  auto P = [&](size_t o_) { return (void*)(base + o_); };

  auto gemm = [&](const void* A, const void* Bt, void* c32, void* co,
                  const void* bias_, const void* sc_, const void* sh_,
                  long M, int N, int K, int lda, int flags) {
    dim3 g((unsigned)(N / 128), (unsigned)((M + 127) / 128));
    gemm_bf16<<<g, 256, 0, stream>>>(A, (const bf16*)Bt, (float*)c32, (bf16*)co,
                                     (const float*)bias_, (const float*)sc_,
                                     (const float*)sh_, (int)M, N, K, lda, flags);
  };
  auto cvt = [&](const float* s, void* d, long n) {
    cvt_k<<<(unsigned)((n + 255) / 256), 256, 0, stream>>>(s, (bf16*)d, n);
  };

  // ---- weight prep ----
  prep_gatW<<<512, 256, 0, stream>>>(gW[0], (bf16*)P(o_w1t), 512);
  prep_gatW<<<256, 256, 0, stream>>>(gW[1], (bf16*)P(o_w2t), 256);
  prep_convw<<<768, 256, 0, stream>>>(cw_[0], (bf16*)P(o_cw1));
  prep_convw<<<768, 256, 0, stream>>>(cw_[1], (bf16*)P(o_cw2));
  cvt(wq, P(o_wq), 65536); cvt(wk, P(o_wk), 65536);
  cvt(wv, P(o_wv), 65536); cvt(wo, P(o_wo), 65536);
  cvt(o1w, P(o_o1w), 65536);
  cvt(Lwih[0][0], P(o_lw0), 131072); cvt(Lwih[0][1], P(o_lw1), 131072);
  cvt(Lwih[1][0], P(o_lw2), 131072); cvt(Lwih[1][1], P(o_lw3), 131072);
  prep_out2<<<128, 256, 0, stream>>>(o2w, (bf16*)P(o_o2p));
  float* sc1 = (float*)P(o_ss); float* sh1 = sc1 + 256;
  float* sc2 = sh1 + 256;       float* sh2 = sc2 + 256;
  prep_scsh<<<1, 256, 0, stream>>>(cb_[0], bng[0], bnb[0], bnm[0], bnv[0], sc1, sh1);
  prep_scsh<<<1, 256, 0, stream>>>(cb_[1], bng[1], bnb[1], bnm[1], bnv[1], sc2, sh2);
  float* bs0 = (float*)P(o_lb);          // layer0: [dirF 512 | dirB 512]
  float* bs1 = bs0 + 1024;               // layer1
  prep_lb<<<4, 256, 0, stream>>>(Lbih[0][0], Lbhh[0][0], Lbih[0][1], Lbhh[0][1], bs0);
  prep_lb<<<4, 256, 0, stream>>>(Lbih[1][0], Lbhh[1][0], Lbih[1][1], Lbhh[1][1], bs1);

  bf16* B1 = (bf16*)P(o_B1);
  bf16* B2 = (bf16*)P(o_B2);   // guard row at row 0; conv space = B2+DD
  bf16* B3 = (bf16*)P(o_B3);
  bf16* lfb[2] = { (bf16*)P(o_lfL), (bf16*)P(o_lfR) };

  // ---- per-hand: GAT x2 -> conv x2 -> lf ----
  for (int hd = 0; hd < 2; hd++) {
    gemm(feats[hd], P(o_w1t), nullptr, B1, nullptr, nullptr, nullptr,
         NLF, 256, 512, 512, 1);                                   // A_F32
    gat_attn<<<NBT, 256, 0, stream>>>(B1, ga[0], adj, B1, 0);      // in-place
    gemm(B1, P(o_w2t), nullptr, B2, nullptr, nullptr, nullptr,
         NLF, 256, 256, 256, 0);
    pad_zero<<<336, 256, 0, stream>>>(B3 + DD);
    gat_attn<<<NBT, 256, 0, stream>>>(B2, ga[1], adj, B3 + DD, 1); // conv layout
    // conv1: single GEMM K=768 over 3 contiguous rows, fused BN+ReLU+padzero
    gemm(B3, P(o_cw1), nullptr, B2 + DD, nullptr, sc1, sh1,
         CONV_M, 256, 768, 256, 8 | 4 | 16);
    // conv2: fused BN+ReLU, write straight to lf layout
    gemm(B2, P(o_cw2), nullptr, lfb[hd], nullptr, sc2, sh2,
         CONV_M, 256, 768, 256, 8 | 4 | 32);
  }

  // ---- cross-hand MHA ----
  // pass1 a_l2r: q=lf_L, k/v=lf_R
  gemm(lfb[0], P(o_wq), nullptr, B1, bq, nullptr, nullptr, NLF, 256, 256, 256, 0);
  gemm(lfb[1], P(o_wk), nullptr, B2, bk, nullptr, nullptr, NLF, 256, 256, 256, 0);
  gemm(lfb[1], P(o_wv), nullptr, B3, bv, nullptr, nullptr, NLF, 256, 256, 256, 0);
  mha_core<<<NBT, 256, 0, stream>>>(B1, B2, B3, B1);               // O in-place
  gemm(B1, P(o_wo), nullptr, B2, bo, nullptr, nullptr, NLF, 256, 256, 256, 0);
  pool_kernel<<<NBT, 256, 0, stream>>>(lfb[1], B2, (bf16*)P(o_re)); // re = rf+0.5*a_l2r
  // pass2 a_r2l: q=lf_R, k/v=lf_L
  gemm(lfb[1], P(o_wq), nullptr, B1, bq, nullptr, nullptr, NLF, 256, 256, 256, 0);
  gemm(lfb[0], P(o_wk), nullptr, B3, bk, nullptr, nullptr, NLF, 256, 256, 256, 0);
  gemm(lfb[0], P(o_wv), nullptr, B2, bv, nullptr, nullptr, NLF, 256, 256, 256, 0);
  mha_core<<<NBT, 256, 0, stream>>>(B1, B3, B2, B1);
  gemm(B1, P(o_wo), nullptr, B3, bo, nullptr, nullptr, NLF, 256, 256, 256, 0);
  pool_kernel<<<NBT, 256, 0, stream>>>(lfb[0], B3, (bf16*)P(o_le)); // le = lf+0.5*a_r2l

  // ---- BiLSTM (xwT aliases B2 region: 32 MB f32, layout [slot][t][b][n]) ----
  float* xw = (float*)P(o_B2);
  auto xslot = [&](int h_, int d_) { return (void*)(xw + ((size_t)(h_ * 2 + d_) << 21)); };
  gemm(P(o_le), P(o_lw0), xslot(0, 0), nullptr, bs0,       nullptr, nullptr, NBT, 512, 256, 256, 64);
  gemm(P(o_le), P(o_lw1), xslot(0, 1), nullptr, bs0 + 512, nullptr, nullptr, NBT, 512, 256, 256, 64);
  gemm(P(o_re), P(o_lw0), xslot(1, 0), nullptr, bs0,       nullptr, nullptr, NBT, 512, 256, 256, 64);
  gemm(P(o_re), P(o_lw1), xslot(1, 1), nullptr, bs0 + 512, nullptr, nullptr, NBT, 512, 256, 256, 64);
  lstm_mfma<<<4, 512, 0, stream>>>(xw, Lwhh[0][0], Lwhh[0][1],
      (bf16*)P(o_h1L), (bf16*)P(o_h1R));
  gemm(P(o_h1L), P(o_lw2), xslot(0, 0), nullptr, bs1,       nullptr, nullptr, NBT, 512, 256, 256, 64);
  gemm(P(o_h1L), P(o_lw3), xslot(0, 1), nullptr, bs1 + 512, nullptr, nullptr, NBT, 512, 256, 256, 64);
  gemm(P(o_h1R), P(o_lw2), xslot(1, 0), nullptr, bs1,       nullptr, nullptr, NBT, 512, 256, 256, 64);
  gemm(P(o_h1R), P(o_lw3), xslot(1, 1), nullptr, bs1 + 512, nullptr, nullptr, NBT, 512, 256, 256, 64);
  lstm_mfma<<<4, 512, 0, stream>>>(xw, Lwhh[1][0], Lwhh[1][1],
      (bf16*)P(o_hoL), (bf16*)P(o_hoR));

  // ---- heads + visibility ----
  for (int hd = 0; hd < 2; hd++) {
    const void* hin = hd ? P(o_hoR) : P(o_hoL);
    gemm(hin, P(o_o1w), nullptr, P(o_t1), o1b, nullptr, nullptr, NBT, 256, 256, 256, 4);
    gemm(P(o_t1), P(o_o2p), P(o_y32), nullptr, nullptr, nullptr, nullptr, NBT, 128, 256, 256, 2);
    finalize_k<<<(NBT * 63 + 255) / 256, 256, 0, stream>>>(
        (const float*)P(o_y32), o2b, vis, (float*)d_out + (size_t)hd * NBT * 63);
  }
}

// Round 8
// 2545.785 us; speedup vs baseline: 1.4124x; 1.4124x over previous
//
#include <hip/hip_runtime.h>

typedef __bf16 bf16;
typedef bf16 bf16x8 __attribute__((ext_vector_type(8)));
typedef float f32x4 __attribute__((ext_vector_type(4)));
typedef _Float16 f16;
typedef f16 f16x8 __attribute__((ext_vector_type(8)));
typedef f16 f16x2 __attribute__((ext_vector_type(2)));

#define NBT 4096      // B*T = 8*512
#define NJ 21
#define NLF 86016     // NBT*NJ
#define DD 256
#define CONV_M 86352  // 168*514
#define SPAD 514
#define CROWS 86528   // 1 guard row + 86352 + overrun slack

// flags: 1=A_F32  2=OUT_F32(C32)  4=RELU  8=BNSS(sc/sh)  16=PADZ(conv layout)
//        32=LFOUT(remap conv row -> lf row)  bias!=null => +bias
__global__ __launch_bounds__(256, 2) void gemm_bf16(
    const void* __restrict__ Av, const bf16* __restrict__ Bt,
    float* __restrict__ C32, bf16* __restrict__ Cout,
    const float* __restrict__ bias, const float* __restrict__ sc,
    const float* __restrict__ sh, int M, int N, int K, int lda, int flags)
{
  __shared__ bf16 As[128][40];
  __shared__ bf16 Bs[128][40];
  const int tid = threadIdx.x;
  const long m0 = (long)blockIdx.y * 128;
  const int n0 = blockIdx.x * 128;
  const int wave = tid >> 6, lane = tid & 63;
  const int wm = (wave & 1) * 64, wn = (wave >> 1) * 64;
  const int lr = tid >> 1, lc = (tid & 1) * 16;
  const int frow = lane & 15, fkb = (lane >> 4) * 8;
  f32x4 acc[4][4] = {};
  for (int k0 = 0; k0 < K; k0 += 32) {
    if (flags & 1) {
      const float* ap = (const float*)Av + (m0 + lr) * (long)lda + (k0 + lc);
      bf16x8 t0, t1;
      #pragma unroll
      for (int u = 0; u < 8; u++) { t0[u] = (bf16)ap[u]; t1[u] = (bf16)ap[8 + u]; }
      *(bf16x8*)(&As[lr][lc])     = t0;
      *(bf16x8*)(&As[lr][lc + 8]) = t1;
    } else {
      const bf16* ap = (const bf16*)Av + (m0 + lr) * (long)lda + (k0 + lc);
      *(bf16x8*)(&As[lr][lc])     = *(const bf16x8*)(ap);
      *(bf16x8*)(&As[lr][lc + 8]) = *(const bf16x8*)(ap + 8);
    }
    const bf16* bp = Bt + (n0 + lr) * (long)K + (k0 + lc);
    *(bf16x8*)(&Bs[lr][lc])     = *(const bf16x8*)(bp);
    *(bf16x8*)(&Bs[lr][lc + 8]) = *(const bf16x8*)(bp + 8);
    __syncthreads();
    bf16x8 af[4], bg[4];
    #pragma unroll
    for (int i = 0; i < 4; i++) af[i] = *(const bf16x8*)(&As[wm + i * 16 + frow][fkb]);
    #pragma unroll
    for (int j = 0; j < 4; j++) bg[j] = *(const bf16x8*)(&Bs[wn + j * 16 + frow][fkb]);
    #pragma unroll
    for (int i = 0; i < 4; i++)
      #pragma unroll
      for (int j = 0; j < 4; j++)
        acc[i][j] = __builtin_amdgcn_mfma_f32_16x16x32_bf16(af[i], bg[j], acc[i][j], 0, 0, 0);
    __syncthreads();
  }
  const int col = lane & 15, rbase = (lane >> 4) * 4;
  #pragma unroll
  for (int i = 0; i < 4; i++) {
    #pragma unroll
    for (int j = 0; j < 4; j++) {
      const int nn = n0 + wn + j * 16 + col;
      #pragma unroll
      for (int r = 0; r < 4; r++) {
        const long mm = m0 + wm + i * 16 + rbase + r;
        if (mm >= M) continue;
        float v = acc[i][j][r];
        if (flags & 2) { C32[mm * (long)N + nn] = v; continue; }
        if (flags & 8) v = v * sc[nn] + sh[nn];
        else if (bias) v += bias[nn];
        if (flags & 4) v = fmaxf(v, 0.f);
        if (flags & 16) {
          const int s = (int)(mm % SPAD);
          if (s == 0 || s == SPAD - 1) v = 0.f;
          Cout[mm * (long)N + nn] = (bf16)v;
        } else if (flags & 32) {
          const long hj = mm / SPAD; const int s = (int)(mm - hj * SPAD);
          if (s == 0 || s == SPAD - 1) continue;
          const long b = hj / NJ; const int j2 = (int)(hj - b * NJ);
          const long dst = (b * 512 + (s - 1)) * NJ + j2;
          Cout[dst * (long)N + nn] = (bf16)v;
        } else {
          Cout[mm * (long)N + nn] = (bf16)v;
        }
      }
    }
  }
}

// ---------------- weight prep (f32 -> bf16) ----------------
__global__ void cvt_k(const float* __restrict__ s, bf16* __restrict__ d, long n) {
  long i = (long)blockIdx.x * 256 + threadIdx.x;
  if (i < n) d[i] = (bf16)s[i];
}
__global__ void prep_gatW(const float* __restrict__ W, bf16* __restrict__ Wt, int F) {
  long idx = (long)blockIdx.x * 256 + threadIdx.x;   // 256*F
  if (idx >= 256L * F) return;
  int n = (int)(idx / F), f = (int)(idx % F);
  Wt[idx] = (bf16)W[((long)(n >> 6) * F + f) * 64 + (n & 63)];
}
__global__ void prep_convw(const float* __restrict__ w, bf16* __restrict__ wp) {
  int idx = blockIdx.x * 256 + threadIdx.x;          // 256*768
  int n = idx / 768, k = idx % 768, tap = k >> 8, i = k & 255;
  wp[idx] = (bf16)w[(n * 256 + i) * 3 + tap];
}
__global__ void prep_out2(const float* __restrict__ w, bf16* __restrict__ wp) {
  int idx = blockIdx.x * 256 + threadIdx.x;          // 128*256
  wp[idx] = (idx < 63 * 256) ? (bf16)w[idx] : (bf16)0.f;
}
__global__ void prep_scsh(const float* __restrict__ cb, const float* __restrict__ g,
                          const float* __restrict__ be, const float* __restrict__ m,
                          const float* __restrict__ v, float* __restrict__ sc,
                          float* __restrict__ sh) {
  int c = threadIdx.x;
  float rs = rsqrtf(v[c] + 1e-5f) * g[c];
  sc[c] = rs; sh[c] = (cb[c] - m[c]) * rs + be[c];
}
__global__ void pad_zero(bf16* __restrict__ convIn) {
  int idx = blockIdx.x * 256 + threadIdx.x;          // 168*2*256
  int hj = idx >> 9, s = ((idx >> 8) & 1) ? (SPAD - 1) : 0, c = idx & 255;
  convIn[((long)hj * SPAD + s) * DD + c] = (bf16)0.f;
}
__global__ void zero_out(float* __restrict__ o, long n) {
  long i = (long)blockIdx.x * 256 + threadIdx.x;
  if (i < n) o[i] = 0.f;
}

// ---------------- GAT attention (per bt block; in-place safe) ----------------
__global__ __launch_bounds__(256) void gat_attn(
    const bf16* __restrict__ Wh, const float* __restrict__ a,
    const float* __restrict__ adj, bf16* __restrict__ out, int convMode)
{
  const int bt = blockIdx.x, tid = threadIdx.x;
  __shared__ float whs[NJ][DD];
  __shared__ float s1[4][NJ], s2[4][NJ];
  __shared__ float att[4][NJ][NJ];
  const long base = (long)bt * NJ * DD;
  for (int i = tid; i < NJ * DD; i += 256)
    whs[i >> 8][i & 255] = (float)Wh[base + i];
  __syncthreads();
  if (tid < 4 * NJ) {
    const int h = tid / NJ, i = tid % NJ;
    float x1 = 0.f, x2 = 0.f;
    for (int d = 0; d < 64; d++) {
      const float w = whs[i][h * 64 + d];
      x1 += w * a[h * 128 + d];
      x2 += w * a[h * 128 + 64 + d];
    }
    s1[h][i] = x1; s2[h][i] = x2;
  }
  __syncthreads();
  for (int idx = tid; idx < 4 * NJ * NJ; idx += 256) {
    const int h = idx / (NJ * NJ), r = idx % (NJ * NJ), i = r / NJ, j = r % NJ;
    float e = s1[h][i] + s2[h][j];
    e = e > 0.f ? e : 0.2f * e;
    att[h][i][j] = (adj[i * NJ + j] > 0.f) ? e : -9e15f;
  }
  __syncthreads();
  if (tid < 4 * NJ) {
    const int h = tid / NJ, i = tid % NJ;
    float mx = -3e38f;
    for (int j = 0; j < NJ; j++) mx = fmaxf(mx, att[h][i][j]);
    float sum = 0.f;
    for (int j = 0; j < NJ; j++) { const float ex = __expf(att[h][i][j] - mx); att[h][i][j] = ex; sum += ex; }
    const float inv = 1.f / sum;
    for (int j = 0; j < NJ; j++) att[h][i][j] *= inv;
  }
  __syncthreads();
  const int b = bt >> 9, t = bt & 511;
  for (int idx = tid; idx < NJ * DD; idx += 256) {
    const int i = idx >> 8, c = idx & 255, h = c >> 6;
    float s = 0.f;
    for (int j = 0; j < NJ; j++) s += att[h][i][j] * whs[j][c];
    s = s > 0.f ? s : (__expf(s) - 1.f);              // ELU
    const long row = convMode ? (((long)(b * NJ + i)) * SPAD + (t + 1)) : ((long)bt * NJ + i);
    out[row * DD + c] = (bf16)s;
  }
}

// ---------------- MHA core (per bt block; O may alias Q) ----------------
__global__ __launch_bounds__(256) void mha_core(
    const bf16* __restrict__ Q, const bf16* __restrict__ K,
    const bf16* __restrict__ V, bf16* __restrict__ O)
{
  const int bt = blockIdx.x, tid = threadIdx.x;
  __shared__ bf16 qs[NJ][DD], ks[NJ][DD], vs[NJ][DD];
  __shared__ float att[4][NJ][NJ];
  const long base = (long)bt * NJ * DD;
  for (int i = tid; i < NJ * DD; i += 256) {
    const int r = i >> 8, c = i & 255;
    qs[r][c] = Q[base + i]; ks[r][c] = K[base + i]; vs[r][c] = V[base + i];
  }
  __syncthreads();
  for (int idx = tid; idx < 4 * NJ * NJ; idx += 256) {
    const int h = idx / (NJ * NJ), r = idx % (NJ * NJ), i = r / NJ, j = r % NJ;
    float s = 0.f;
    for (int d = 0; d < 64; d++) s += (float)qs[i][h * 64 + d] * (float)ks[j][h * 64 + d];
    att[h][i][j] = s * 0.125f;
  }
  __syncthreads();
  if (tid < 4 * NJ) {
    const int h = tid / NJ, i = tid % NJ;
    float mx = -3e38f;
    for (int j = 0; j < NJ; j++) mx = fmaxf(mx, att[h][i][j]);
    float sum = 0.f;
    for (int j = 0; j < NJ; j++) { const float ex = __expf(att[h][i][j] - mx); att[h][i][j] = ex; sum += ex; }
    const float inv = 1.f / sum;
    for (int j = 0; j < NJ; j++) att[h][i][j] *= inv;
  }
  __syncthreads();
  for (int idx = tid; idx < NJ * DD; idx += 256) {
    const int i = idx >> 8, c = idx & 255, h = c >> 6;
    float s = 0.f;
    for (int j = 0; j < NJ; j++) s += att[h][i][j] * (float)vs[j][c];
    O[base + i * DD + c] = (bf16)s;
  }
}

// ---------------- residual + joint-mean pool ----------------
__global__ __launch_bounds__(256) void pool_kernel(
    const bf16* __restrict__ lf, const bf16* __restrict__ ao, bf16* __restrict__ o)
{
  const int bt = blockIdx.x, c = threadIdx.x;
  float s = 0.f;
  for (int j = 0; j < NJ; j++) {
    const long r = ((long)bt * NJ + j) * DD + c;
    s += (float)lf[r] + 0.5f * (float)ao[r];
  }
  o[(long)bt * DD + c] = (bf16)(s * (1.f / 21.f));
}

// ---------------- persistent LSTM: weights in LDS as f16 ----------------
// R2-R5 post-mortem: per-thread register weights were rematerialized -> L1
// reload BW wall (256KB/step/CU / 64B/clk ~ 4000cyc/step, matches measured).
// R6/R7 MFMA version: unpredictable ~3300cyc/step. This design keeps whh in
// 139KB of LDS (explicit, allocator can't reload it from global); per step:
// 16 ds_read_b128 weights (stride 272B: lane granule = lane%8 -> conflict-
// free) + 16 broadcast h reads + 64 v_dot2_f32_f16 in 4 rotating accums.
__global__ __launch_bounds__(512, 1) void lstm_lds(
    const float* __restrict__ xw,
    const float* __restrict__ whhF, const float* __restrict__ whhB,
    const float* __restrict__ bihF, const float* __restrict__ bhhF,
    const float* __restrict__ bihB, const float* __restrict__ bhhB,
    bf16* __restrict__ outL, bf16* __restrict__ outR)
{
  const int wg = blockIdx.x;
  const int hand = wg >> 4, dir = (wg >> 3) & 1, b = wg & 7;
  const int tid = threadIdx.x;
  const float* whh = dir ? whhB : whhF;

  __shared__ f16 whhs[512][136];   // 139,264 B
  __shared__ f16 hbuf[136];
  __shared__ float gsb[512];

  for (int i = tid; i < 512 * 128; i += 512)        // coalesced f32 -> f16 LDS
    whhs[i >> 7][i & 127] = (f16)whh[i];
  if (tid < 136) hbuf[tid] = (f16)0.f;
  const float bias = (dir ? bihB : bihF)[tid] + (dir ? bhhB : bhhF)[tid];
  float c = 0.f;
  const float* xp = xw + (((long)(hand * 2 + dir)) * NBT + (long)b * 512) * 512;
  bf16* outp = hand ? outR : outL;
  float xv = xp[(long)(dir ? 511 : 0) * 512 + tid];  // prefetch step 0
  __syncthreads();

  for (int s = 0; s < 512; s++) {
    const int t = dir ? (511 - s) : s;
    const int tn = dir ? (510 - s) : (s + 1);
    float xnext = 0.f;
    if (s < 511) xnext = xp[(long)tn * 512 + tid];   // prefetch next step
    float a0 = xv + bias, a1 = 0.f, a2 = 0.f, a3 = 0.f;
    const f16* wrow = &whhs[tid][0];
    #pragma unroll
    for (int k8 = 0; k8 < 16; k8++) {
      const f16x8 wv = *(const f16x8*)(wrow + k8 * 8);
      const f16x8 hv = *(const f16x8*)(&hbuf[k8 * 8]);
      a0 = __builtin_amdgcn_fdot2(__builtin_shufflevector(wv, wv, 0, 1),
                                  __builtin_shufflevector(hv, hv, 0, 1), a0, false);
      a1 = __builtin_amdgcn_fdot2(__builtin_shufflevector(wv, wv, 2, 3),
                                  __builtin_shufflevector(hv, hv, 2, 3), a1, false);
      a2 = __builtin_amdgcn_fdot2(__builtin_shufflevector(wv, wv, 4, 5),
                                  __builtin_shufflevector(hv, hv, 4, 5), a2, false);
      a3 = __builtin_amdgcn_fdot2(__builtin_shufflevector(wv, wv, 6, 7),
                                  __builtin_shufflevector(hv, hv, 6, 7), a3, false);
    }
    gsb[tid] = (a0 + a1) + (a2 + a3);
    __syncthreads();
    if (tid < 128) {
      const float ig = gsb[tid], fg = gsb[tid + 128], gg = gsb[tid + 256], og = gsb[tid + 384];
      const float si = __builtin_amdgcn_rcpf(1.f + __expf(-ig));
      const float sf = __builtin_amdgcn_rcpf(1.f + __expf(-fg));
      const float so = __builtin_amdgcn_rcpf(1.f + __expf(-og));
      const float tg = 1.f - 2.f * __builtin_amdgcn_rcpf(1.f + __expf(2.f * gg));
      c = sf * c + si * tg;
      const float tc = 1.f - 2.f * __builtin_amdgcn_rcpf(1.f + __expf(2.f * c));
      const float h = so * tc;
      hbuf[tid] = (f16)h;
      outp[((long)b * 512 + t) * 256 + dir * 128 + tid] = (bf16)h;
    }
    __syncthreads();
    xv = xnext;
  }
}

// ---------------- final: +bias, *visibility ----------------
__global__ __launch_bounds__(256) void finalize_k(
    const float* __restrict__ y, const float* __restrict__ b2,
    const float* __restrict__ vis, float* __restrict__ out)
{
  const int idx = blockIdx.x * 256 + threadIdx.x;
  if (idx >= NBT * 63) return;
  const int c = idx % 63; const int bt = idx / 63;
  out[idx] = (y[(long)bt * 128 + c] + b2[c]) * vis[bt * 21 + (c / 3)];
}

extern "C" void kernel_launch(void* const* d_in, const int* in_sizes, int n_in,
                              void* d_out, int out_size, void* d_ws, size_t ws_size,
                              hipStream_t stream) {
  (void)in_sizes; (void)n_in;
  const float* feats[2] = { (const float*)d_in[0], (const float*)d_in[1] };
  const float* adj  = (const float*)d_in[2];
  const float* vis  = (const float*)d_in[3];
  const float* gW[2] = { (const float*)d_in[4], (const float*)d_in[6] };
  const float* ga[2] = { (const float*)d_in[5], (const float*)d_in[7] };
  const float* cw_[2] = { (const float*)d_in[8],  (const float*)d_in[10] };
  const float* cb_[2] = { (const float*)d_in[9],  (const float*)d_in[11] };
  const float* bng[2] = { (const float*)d_in[12], (const float*)d_in[16] };
  const float* bnb[2] = { (const float*)d_in[13], (const float*)d_in[17] };
  const float* bnm[2] = { (const float*)d_in[14], (const float*)d_in[18] };
  const float* bnv[2] = { (const float*)d_in[15], (const float*)d_in[19] };
  const float* wq = (const float*)d_in[20], *wk = (const float*)d_in[21];
  const float* wv = (const float*)d_in[22], *wo = (const float*)d_in[23];
  const float* bq = (const float*)d_in[24], *bk = (const float*)d_in[25];
  const float* bv = (const float*)d_in[26], *bo = (const float*)d_in[27];
  const float* Lwih[2][2] = { { (const float*)d_in[28], (const float*)d_in[32] },
                              { (const float*)d_in[36], (const float*)d_in[40] } };
  const float* Lwhh[2][2] = { { (const float*)d_in[29], (const float*)d_in[33] },
                              { (const float*)d_in[37], (const float*)d_in[41] } };
  const float* Lbih[2][2] = { { (const float*)d_in[30], (const float*)d_in[34] },
                              { (const float*)d_in[38], (const float*)d_in[42] } };
  const float* Lbhh[2][2] = { { (const float*)d_in[31], (const float*)d_in[35] },
                              { (const float*)d_in[39], (const float*)d_in[43] } };
  const float* o1w = (const float*)d_in[44], *o1b = (const float*)d_in[45];
  const float* o2w = (const float*)d_in[46], *o2b = (const float*)d_in[47];

  char* base = (char*)d_ws;
  size_t off = 0;
  auto alloc = [&](size_t b) { size_t r = off; off += (b + 1023) & ~(size_t)1023; return r; };
  const size_t SZ_LF  = (size_t)NLF * DD * 2;     // 44.04 MB
  const size_t SZ_CNV = (size_t)CROWS * DD * 2;   // 44.30 MB
  const size_t SZ_BT  = (size_t)NBT * DD * 2;     // 2.10 MB
  const size_t o_w1t = alloc((size_t)256 * 512 * 2);
  const size_t o_w2t = alloc((size_t)256 * 256 * 2);
  const size_t o_cw1 = alloc((size_t)256 * 768 * 2);
  const size_t o_cw2 = alloc((size_t)256 * 768 * 2);
  const size_t o_wq  = alloc((size_t)256 * 256 * 2);
  const size_t o_wk  = alloc((size_t)256 * 256 * 2);
  const size_t o_wv  = alloc((size_t)256 * 256 * 2);
  const size_t o_wo  = alloc((size_t)256 * 256 * 2);
  const size_t o_o1w = alloc((size_t)256 * 256 * 2);
  const size_t o_o2p = alloc((size_t)128 * 256 * 2);
  const size_t o_lw0 = alloc((size_t)512 * 256 * 2);
  const size_t o_lw1 = alloc((size_t)512 * 256 * 2);
  const size_t o_lw2 = alloc((size_t)512 * 256 * 2);
  const size_t o_lw3 = alloc((size_t)512 * 256 * 2);
  const size_t o_ss  = alloc((size_t)4 * 256 * 4);
  const size_t o_B1  = alloc(SZ_LF);
  const size_t o_B2  = alloc(SZ_CNV);
  const size_t o_B3  = alloc(SZ_CNV);
  const size_t o_lfL = alloc(SZ_LF);
  const size_t o_lfR = alloc(SZ_LF);
  const size_t o_le  = alloc(SZ_BT);
  const size_t o_re  = alloc(SZ_BT);
  const size_t o_h1L = alloc(SZ_BT);
  const size_t o_h1R = alloc(SZ_BT);
  const size_t o_hoL = alloc(SZ_BT);
  const size_t o_hoR = alloc(SZ_BT);
  const size_t o_t1  = alloc(SZ_BT);
  const size_t o_y32 = alloc((size_t)NBT * 128 * 4);
  const size_t NEED = off;
  if (ws_size < NEED) {   // graceful diagnostic: zero output, clean absmax-fail
    zero_out<<<(out_size + 255) / 256, 256, 0, stream>>>((float*)d_out, out_size);
    return;
  }
  auto P = [&](size_t o_) { return (void*)(base + o_); };

  auto gemm = [&](const void* A, const void* Bt, void* c32, void* co,
                  const void* bias_, const void* sc_, const void* sh_,
                  long M, int N, int K, int lda, int flags) {
    dim3 g((unsigned)(N / 128), (unsigned)((M + 127) / 128));
    gemm_bf16<<<g, 256, 0, stream>>>(A, (const bf16*)Bt, (float*)c32, (bf16*)co,
                                     (const float*)bias_, (const float*)sc_,
                                     (const float*)sh_, (int)M, N, K, lda, flags);
  };
  auto cvt = [&](const float* s, void* d, long n) {
    cvt_k<<<(unsigned)((n + 255) / 256), 256, 0, stream>>>(s, (bf16*)d, n);
  };

  // ---- weight prep ----
  prep_gatW<<<512, 256, 0, stream>>>(gW[0], (bf16*)P(o_w1t), 512);
  prep_gatW<<<256, 256, 0, stream>>>(gW[1], (bf16*)P(o_w2t), 256);
  prep_convw<<<768, 256, 0, stream>>>(cw_[0], (bf16*)P(o_cw1));
  prep_convw<<<768, 256, 0, stream>>>(cw_[1], (bf16*)P(o_cw2));
  cvt(wq, P(o_wq), 65536); cvt(wk, P(o_wk), 65536);
  cvt(wv, P(o_wv), 65536); cvt(wo, P(o_wo), 65536);
  cvt(o1w, P(o_o1w), 65536);
  cvt(Lwih[0][0], P(o_lw0), 131072); cvt(Lwih[0][1], P(o_lw1), 131072);
  cvt(Lwih[1][0], P(o_lw2), 131072); cvt(Lwih[1][1], P(o_lw3), 131072);
  prep_out2<<<128, 256, 0, stream>>>(o2w, (bf16*)P(o_o2p));
  float* sc1 = (float*)P(o_ss); float* sh1 = sc1 + 256;
  float* sc2 = sh1 + 256;       float* sh2 = sc2 + 256;
  prep_scsh<<<1, 256, 0, stream>>>(cb_[0], bng[0], bnb[0], bnm[0], bnv[0], sc1, sh1);
  prep_scsh<<<1, 256, 0, stream>>>(cb_[1], bng[1], bnb[1], bnm[1], bnv[1], sc2, sh2);

  bf16* B1 = (bf16*)P(o_B1);
  bf16* B2 = (bf16*)P(o_B2);   // guard row at row 0; conv space = B2+DD
  bf16* B3 = (bf16*)P(o_B3);
  bf16* lfb[2] = { (bf16*)P(o_lfL), (bf16*)P(o_lfR) };

  // ---- per-hand: GAT x2 -> conv x2 -> lf ----
  for (int hd = 0; hd < 2; hd++) {
    gemm(feats[hd], P(o_w1t), nullptr, B1, nullptr, nullptr, nullptr,
         NLF, 256, 512, 512, 1);                                   // A_F32
    gat_attn<<<NBT, 256, 0, stream>>>(B1, ga[0], adj, B1, 0);      // in-place
    gemm(B1, P(o_w2t), nullptr, B2, nullptr, nullptr, nullptr,
         NLF, 256, 256, 256, 0);
    pad_zero<<<336, 256, 0, stream>>>(B3 + DD);
    gat_attn<<<NBT, 256, 0, stream>>>(B2, ga[1], adj, B3 + DD, 1); // conv layout
    // conv1: single GEMM K=768 over 3 contiguous rows, fused BN+ReLU+padzero
    gemm(B3, P(o_cw1), nullptr, B2 + DD, nullptr, sc1, sh1,
         CONV_M, 256, 768, 256, 8 | 4 | 16);
    // conv2: fused BN+ReLU, write straight to lf layout
    gemm(B2, P(o_cw2), nullptr, lfb[hd], nullptr, sc2, sh2,
         CONV_M, 256, 768, 256, 8 | 4 | 32);
  }

  // ---- cross-hand MHA ----
  // pass1 a_l2r: q=lf_L, k/v=lf_R
  gemm(lfb[0], P(o_wq), nullptr, B1, bq, nullptr, nullptr, NLF, 256, 256, 256, 0);
  gemm(lfb[1], P(o_wk), nullptr, B2, bk, nullptr, nullptr, NLF, 256, 256, 256, 0);
  gemm(lfb[1], P(o_wv), nullptr, B3, bv, nullptr, nullptr, NLF, 256, 256, 256, 0);
  mha_core<<<NBT, 256, 0, stream>>>(B1, B2, B3, B1);               // O in-place
  gemm(B1, P(o_wo), nullptr, B2, bo, nullptr, nullptr, NLF, 256, 256, 256, 0);
  pool_kernel<<<NBT, 256, 0, stream>>>(lfb[1], B2, (bf16*)P(o_re)); // re = rf+0.5*a_l2r
  // pass2 a_r2l: q=lf_R, k/v=lf_L
  gemm(lfb[1], P(o_wq), nullptr, B1, bq, nullptr, nullptr, NLF, 256, 256, 256, 0);
  gemm(lfb[0], P(o_wk), nullptr, B3, bk, nullptr, nullptr, NLF, 256, 256, 256, 0);
  gemm(lfb[0], P(o_wv), nullptr, B2, bv, nullptr, nullptr, NLF, 256, 256, 256, 0);
  mha_core<<<NBT, 256, 0, stream>>>(B1, B3, B2, B1);
  gemm(B1, P(o_wo), nullptr, B3, bo, nullptr, nullptr, NLF, 256, 256, 256, 0);
  pool_kernel<<<NBT, 256, 0, stream>>>(lfb[0], B3, (bf16*)P(o_le)); // le = lf+0.5*a_r2l

  // ---- BiLSTM (xw aliases B2 region: 33.5 MB f32) ----
  float* xw = (float*)P(o_B2);
  auto xslot = [&](int h_, int d_) { return (void*)(xw + ((size_t)(h_ * 2 + d_)) * NBT * 512); };
  gemm(P(o_le), P(o_lw0), xslot(0, 0), nullptr, nullptr, nullptr, nullptr, NBT, 512, 256, 256, 2);
  gemm(P(o_le), P(o_lw1), xslot(0, 1), nullptr, nullptr, nullptr, nullptr, NBT, 512, 256, 256, 2);
  gemm(P(o_re), P(o_lw0), xslot(1, 0), nullptr, nullptr, nullptr, nullptr, NBT, 512, 256, 256, 2);
  gemm(P(o_re), P(o_lw1), xslot(1, 1), nullptr, nullptr, nullptr, nullptr, NBT, 512, 256, 256, 2);
  lstm_lds<<<32, 512, 0, stream>>>(xw, Lwhh[0][0], Lwhh[0][1],
      Lbih[0][0], Lbhh[0][0], Lbih[0][1], Lbhh[0][1],
      (bf16*)P(o_h1L), (bf16*)P(o_h1R));
  gemm(P(o_h1L), P(o_lw2), xslot(0, 0), nullptr, nullptr, nullptr, nullptr, NBT, 512, 256, 256, 2);
  gemm(P(o_h1L), P(o_lw3), xslot(0, 1), nullptr, nullptr, nullptr, nullptr, NBT, 512, 256, 256, 2);
  gemm(P(o_h1R), P(o_lw2), xslot(1, 0), nullptr, nullptr, nullptr, nullptr, NBT, 512, 256, 256, 2);
  gemm(P(o_h1R), P(o_lw3), xslot(1, 1), nullptr, nullptr, nullptr, nullptr, NBT, 512, 256, 256, 2);
  lstm_lds<<<32, 512, 0, stream>>>(xw, Lwhh[1][0], Lwhh[1][1],
      Lbih[1][0], Lbhh[1][0], Lbih[1][1], Lbhh[1][1],
      (bf16*)P(o_hoL), (bf16*)P(o_hoR));

  // ---- heads + visibility ----
  for (int hd = 0; hd < 2; hd++) {
    const void* hin = hd ? P(o_hoR) : P(o_hoL);
    gemm(hin, P(o_o1w), nullptr, P(o_t1), o1b, nullptr, nullptr, NBT, 256, 256, 256, 4);
    gemm(P(o_t1), P(o_o2p), P(o_y32), nullptr, nullptr, nullptr, nullptr, NBT, 128, 256, 256, 2);
    finalize_k<<<(NBT * 63 + 255) / 256, 256, 0, stream>>>(
        (const float*)P(o_y32), o2b, vis, (float*)d_out + (size_t)hd * NBT * 63);
  }
}

// Round 9
// 2424.876 us; speedup vs baseline: 1.4829x; 1.0499x over previous
//
#include <hip/hip_runtime.h>

typedef __bf16 bf16;
typedef bf16 bf16x8 __attribute__((ext_vector_type(8)));
typedef float f32x4 __attribute__((ext_vector_type(4)));
typedef _Float16 f16;
typedef f16 f16x8 __attribute__((ext_vector_type(8)));
typedef f16 f16x2 __attribute__((ext_vector_type(2)));

#define NBT 4096      // B*T = 8*512
#define NJ 21
#define NLF 86016     // NBT*NJ
#define DD 256
#define CONV_M 86352  // 168*514
#define SPAD 514
#define CROWS 86528   // 1 guard row + 86352 + overrun slack

// flags: 1=A_F32  2=OUT_F32(C32)  4=RELU  8=BNSS(sc/sh)  16=PADZ(conv layout)
//        32=LFOUT(remap conv row -> lf row)  bias!=null => +bias
__global__ __launch_bounds__(256, 2) void gemm_bf16(
    const void* __restrict__ Av, const bf16* __restrict__ Bt,
    float* __restrict__ C32, bf16* __restrict__ Cout,
    const float* __restrict__ bias, const float* __restrict__ sc,
    const float* __restrict__ sh, int M, int N, int K, int lda, int flags)
{
  __shared__ bf16 As[128][40];
  __shared__ bf16 Bs[128][40];
  const int tid = threadIdx.x;
  const long m0 = (long)blockIdx.y * 128;
  const int n0 = blockIdx.x * 128;
  const int wave = tid >> 6, lane = tid & 63;
  const int wm = (wave & 1) * 64, wn = (wave >> 1) * 64;
  const int lr = tid >> 1, lc = (tid & 1) * 16;
  const int frow = lane & 15, fkb = (lane >> 4) * 8;
  f32x4 acc[4][4] = {};
  for (int k0 = 0; k0 < K; k0 += 32) {
    if (flags & 1) {
      const float* ap = (const float*)Av + (m0 + lr) * (long)lda + (k0 + lc);
      bf16x8 t0, t1;
      #pragma unroll
      for (int u = 0; u < 8; u++) { t0[u] = (bf16)ap[u]; t1[u] = (bf16)ap[8 + u]; }
      *(bf16x8*)(&As[lr][lc])     = t0;
      *(bf16x8*)(&As[lr][lc + 8]) = t1;
    } else {
      const bf16* ap = (const bf16*)Av + (m0 + lr) * (long)lda + (k0 + lc);
      *(bf16x8*)(&As[lr][lc])     = *(const bf16x8*)(ap);
      *(bf16x8*)(&As[lr][lc + 8]) = *(const bf16x8*)(ap + 8);
    }
    const bf16* bp = Bt + (n0 + lr) * (long)K + (k0 + lc);
    *(bf16x8*)(&Bs[lr][lc])     = *(const bf16x8*)(bp);
    *(bf16x8*)(&Bs[lr][lc + 8]) = *(const bf16x8*)(bp + 8);
    __syncthreads();
    bf16x8 af[4], bg[4];
    #pragma unroll
    for (int i = 0; i < 4; i++) af[i] = *(const bf16x8*)(&As[wm + i * 16 + frow][fkb]);
    #pragma unroll
    for (int j = 0; j < 4; j++) bg[j] = *(const bf16x8*)(&Bs[wn + j * 16 + frow][fkb]);
    #pragma unroll
    for (int i = 0; i < 4; i++)
      #pragma unroll
      for (int j = 0; j < 4; j++)
        acc[i][j] = __builtin_amdgcn_mfma_f32_16x16x32_bf16(af[i], bg[j], acc[i][j], 0, 0, 0);
    __syncthreads();
  }
  const int col = lane & 15, rbase = (lane >> 4) * 4;
  #pragma unroll
  for (int i = 0; i < 4; i++) {
    #pragma unroll
    for (int j = 0; j < 4; j++) {
      const int nn = n0 + wn + j * 16 + col;
      #pragma unroll
      for (int r = 0; r < 4; r++) {
        const long mm = m0 + wm + i * 16 + rbase + r;
        if (mm >= M) continue;
        float v = acc[i][j][r];
        if (flags & 2) { C32[mm * (long)N + nn] = v; continue; }
        if (flags & 8) v = v * sc[nn] + sh[nn];
        else if (bias) v += bias[nn];
        if (flags & 4) v = fmaxf(v, 0.f);
        if (flags & 16) {
          const int s = (int)(mm % SPAD);
          if (s == 0 || s == SPAD - 1) v = 0.f;
          Cout[mm * (long)N + nn] = (bf16)v;
        } else if (flags & 32) {
          const long hj = mm / SPAD; const int s = (int)(mm - hj * SPAD);
          if (s == 0 || s == SPAD - 1) continue;
          const long b = hj / NJ; const int j2 = (int)(hj - b * NJ);
          const long dst = (b * 512 + (s - 1)) * NJ + j2;
          Cout[dst * (long)N + nn] = (bf16)v;
        } else {
          Cout[mm * (long)N + nn] = (bf16)v;
        }
      }
    }
  }
}

// ---------------- weight prep (f32 -> bf16) ----------------
__global__ void cvt_k(const float* __restrict__ s, bf16* __restrict__ d, long n) {
  long i = (long)blockIdx.x * 256 + threadIdx.x;
  if (i < n) d[i] = (bf16)s[i];
}
__global__ void prep_gatW(const float* __restrict__ W, bf16* __restrict__ Wt, int F) {
  long idx = (long)blockIdx.x * 256 + threadIdx.x;   // 256*F
  if (idx >= 256L * F) return;
  int n = (int)(idx / F), f = (int)(idx % F);
  Wt[idx] = (bf16)W[((long)(n >> 6) * F + f) * 64 + (n & 63)];
}
__global__ void prep_convw(const float* __restrict__ w, bf16* __restrict__ wp) {
  int idx = blockIdx.x * 256 + threadIdx.x;          // 256*768
  int n = idx / 768, k = idx % 768, tap = k >> 8, i = k & 255;
  wp[idx] = (bf16)w[(n * 256 + i) * 3 + tap];
}
__global__ void prep_out2(const float* __restrict__ w, bf16* __restrict__ wp) {
  int idx = blockIdx.x * 256 + threadIdx.x;          // 128*256
  wp[idx] = (idx < 63 * 256) ? (bf16)w[idx] : (bf16)0.f;
}
__global__ void prep_scsh(const float* __restrict__ cb, const float* __restrict__ g,
                          const float* __restrict__ be, const float* __restrict__ m,
                          const float* __restrict__ v, float* __restrict__ sc,
                          float* __restrict__ sh) {
  int c = threadIdx.x;
  float rs = rsqrtf(v[c] + 1e-5f) * g[c];
  sc[c] = rs; sh[c] = (cb[c] - m[c]) * rs + be[c];
}
__global__ void pad_zero(bf16* __restrict__ convIn) {
  int idx = blockIdx.x * 256 + threadIdx.x;          // 168*2*256
  int hj = idx >> 9, s = ((idx >> 8) & 1) ? (SPAD - 1) : 0, c = idx & 255;
  convIn[((long)hj * SPAD + s) * DD + c] = (bf16)0.f;
}
__global__ void zero_out(float* __restrict__ o, long n) {
  long i = (long)blockIdx.x * 256 + threadIdx.x;
  if (i < n) o[i] = 0.f;
}

// ---------------- GAT attention (per bt block; in-place safe) ----------------
__global__ __launch_bounds__(256) void gat_attn(
    const bf16* __restrict__ Wh, const float* __restrict__ a,
    const float* __restrict__ adj, bf16* __restrict__ out, int convMode)
{
  const int bt = blockIdx.x, tid = threadIdx.x;
  __shared__ float whs[NJ][DD];
  __shared__ float s1[4][NJ], s2[4][NJ];
  __shared__ float att[4][NJ][NJ];
  const long base = (long)bt * NJ * DD;
  for (int i = tid; i < NJ * DD; i += 256)
    whs[i >> 8][i & 255] = (float)Wh[base + i];
  __syncthreads();
  if (tid < 4 * NJ) {
    const int h = tid / NJ, i = tid % NJ;
    float x1 = 0.f, x2 = 0.f;
    for (int d = 0; d < 64; d++) {
      const float w = whs[i][h * 64 + d];
      x1 += w * a[h * 128 + d];
      x2 += w * a[h * 128 + 64 + d];
    }
    s1[h][i] = x1; s2[h][i] = x2;
  }
  __syncthreads();
  for (int idx = tid; idx < 4 * NJ * NJ; idx += 256) {
    const int h = idx / (NJ * NJ), r = idx % (NJ * NJ), i = r / NJ, j = r % NJ;
    float e = s1[h][i] + s2[h][j];
    e = e > 0.f ? e : 0.2f * e;
    att[h][i][j] = (adj[i * NJ + j] > 0.f) ? e : -9e15f;
  }
  __syncthreads();
  if (tid < 4 * NJ) {
    const int h = tid / NJ, i = tid % NJ;
    float mx = -3e38f;
    for (int j = 0; j < NJ; j++) mx = fmaxf(mx, att[h][i][j]);
    float sum = 0.f;
    for (int j = 0; j < NJ; j++) { const float ex = __expf(att[h][i][j] - mx); att[h][i][j] = ex; sum += ex; }
    const float inv = 1.f / sum;
    for (int j = 0; j < NJ; j++) att[h][i][j] *= inv;
  }
  __syncthreads();
  const int b = bt >> 9, t = bt & 511;
  for (int idx = tid; idx < NJ * DD; idx += 256) {
    const int i = idx >> 8, c = idx & 255, h = c >> 6;
    float s = 0.f;
    for (int j = 0; j < NJ; j++) s += att[h][i][j] * whs[j][c];
    s = s > 0.f ? s : (__expf(s) - 1.f);              // ELU
    const long row = convMode ? (((long)(b * NJ + i)) * SPAD + (t + 1)) : ((long)bt * NJ + i);
    out[row * DD + c] = (bf16)s;
  }
}

// ---------------- MHA core (per bt block; O may alias Q) ----------------
__global__ __launch_bounds__(256) void mha_core(
    const bf16* __restrict__ Q, const bf16* __restrict__ K,
    const bf16* __restrict__ V, bf16* __restrict__ O)
{
  const int bt = blockIdx.x, tid = threadIdx.x;
  __shared__ bf16 qs[NJ][DD], ks[NJ][DD], vs[NJ][DD];
  __shared__ float att[4][NJ][NJ];
  const long base = (long)bt * NJ * DD;
  for (int i = tid; i < NJ * DD; i += 256) {
    const int r = i >> 8, c = i & 255;
    qs[r][c] = Q[base + i]; ks[r][c] = K[base + i]; vs[r][c] = V[base + i];
  }
  __syncthreads();
  for (int idx = tid; idx < 4 * NJ * NJ; idx += 256) {
    const int h = idx / (NJ * NJ), r = idx % (NJ * NJ), i = r / NJ, j = r % NJ;
    float s = 0.f;
    for (int d = 0; d < 64; d++) s += (float)qs[i][h * 64 + d] * (float)ks[j][h * 64 + d];
    att[h][i][j] = s * 0.125f;
  }
  __syncthreads();
  if (tid < 4 * NJ) {
    const int h = tid / NJ, i = tid % NJ;
    float mx = -3e38f;
    for (int j = 0; j < NJ; j++) mx = fmaxf(mx, att[h][i][j]);
    float sum = 0.f;
    for (int j = 0; j < NJ; j++) { const float ex = __expf(att[h][i][j] - mx); att[h][i][j] = ex; sum += ex; }
    const float inv = 1.f / sum;
    for (int j = 0; j < NJ; j++) att[h][i][j] *= inv;
  }
  __syncthreads();
  for (int idx = tid; idx < NJ * DD; idx += 256) {
    const int i = idx >> 8, c = idx & 255, h = c >> 6;
    float s = 0.f;
    for (int j = 0; j < NJ; j++) s += att[h][i][j] * (float)vs[j][c];
    O[base + i * DD + c] = (bf16)s;
  }
}

// ---------------- residual + joint-mean pool ----------------
__global__ __launch_bounds__(256) void pool_kernel(
    const bf16* __restrict__ lf, const bf16* __restrict__ ao, bf16* __restrict__ o)
{
  const int bt = blockIdx.x, c = threadIdx.x;
  float s = 0.f;
  for (int j = 0; j < NJ; j++) {
    const long r = ((long)bt * NJ + j) * DD + c;
    s += (float)lf[r] + 0.5f * (float)ao[r];
  }
  o[(long)bt * DD + c] = (bf16)(s * (1.f / 21.f));
}

// ---------------- persistent LSTM: weights in LDS + registers ----------------
// R8 measured 1790cyc/step: ~768 LDS weight re-read + ~400 __syncthreads
// vmcnt drains (xw prefetch is HBM, ~900cyc) + gate/barrier. This round:
// (1) weights are LOOP-INVARIANT -> 16 named f16x8 (64 VGPR) loaded from LDS
//     pre-loop. LDS=139KB caps occupancy at 1 WG/CU (2 waves/SIMD), so the
//     allocator has no occupancy incentive to sink them; if it does sink,
//     they come back from LDS = status quo (free bet).
// (2) lgkmcnt-only barriers: all cross-thread data is LDS; the xw load's
//     consumer gets compiler-inserted vmcnt -> drains removed.
#define REP16(X) X(0) X(1) X(2) X(3) X(4) X(5) X(6) X(7) X(8) X(9) X(10) X(11) \
  X(12) X(13) X(14) X(15)

#define LDS_FENCE() do { \
  asm volatile("s_waitcnt lgkmcnt(0)" ::: "memory"); \
  __builtin_amdgcn_sched_barrier(0); \
  __builtin_amdgcn_s_barrier(); \
  __builtin_amdgcn_sched_barrier(0); \
} while (0)

__global__ __launch_bounds__(512, 1) void lstm_lds(
    const float* __restrict__ xw,
    const float* __restrict__ whhF, const float* __restrict__ whhB,
    const float* __restrict__ bihF, const float* __restrict__ bhhF,
    const float* __restrict__ bihB, const float* __restrict__ bhhB,
    bf16* __restrict__ outL, bf16* __restrict__ outR)
{
  const int wg = blockIdx.x;
  const int hand = wg >> 4, dir = (wg >> 3) & 1, b = wg & 7;
  const int tid = threadIdx.x;
  const float* whh = dir ? whhB : whhF;

  __shared__ f16 whhs[512][136];   // 139,264 B -> occupancy capped at 1 WG/CU
  __shared__ f16 hbuf[136];
  __shared__ float gsb[512];

  for (int i = tid; i < 512 * 128; i += 512)        // coalesced f32 -> f16 LDS
    whhs[i >> 7][i & 127] = (f16)whh[i];
  if (tid < 136) hbuf[tid] = (f16)0.f;
  const float bias = (dir ? bihB : bihF)[tid] + (dir ? bhhB : bhhF)[tid];
  float c = 0.f;
  const float* xp = xw + (((long)(hand * 2 + dir)) * NBT + (long)b * 512) * 512;
  bf16* outp = hand ? outR : outL;
  float xv = xp[(long)(dir ? 511 : 0) * 512 + tid];  // prefetch step 0
  __syncthreads();

  // loop-invariant weight row -> named registers (64 VGPRs)
  const f16* wrow = &whhs[tid][0];
#define WRD(i) f16x8 w##i = *(const f16x8*)(wrow + (i) * 8);
  REP16(WRD)
#undef WRD

  for (int s = 0; s < 512; s++) {
    const int t = dir ? (511 - s) : s;
    const int tn = dir ? (510 - s) : (s + 1);
    float xnext = 0.f;
    if (s < 511) xnext = xp[(long)tn * 512 + tid];   // prefetch next step
    float a0 = xv + bias, a1 = 0.f, a2 = 0.f, a3 = 0.f;
#define WDOT(i) { \
    const f16x8 hv = *(const f16x8*)(&hbuf[(i) * 8]); \
    a0 = __builtin_amdgcn_fdot2(__builtin_shufflevector(w##i, w##i, 0, 1), \
                                __builtin_shufflevector(hv, hv, 0, 1), a0, false); \
    a1 = __builtin_amdgcn_fdot2(__builtin_shufflevector(w##i, w##i, 2, 3), \
                                __builtin_shufflevector(hv, hv, 2, 3), a1, false); \
    a2 = __builtin_amdgcn_fdot2(__builtin_shufflevector(w##i, w##i, 4, 5), \
                                __builtin_shufflevector(hv, hv, 4, 5), a2, false); \
    a3 = __builtin_amdgcn_fdot2(__builtin_shufflevector(w##i, w##i, 6, 7), \
                                __builtin_shufflevector(hv, hv, 6, 7), a3, false); }
    REP16(WDOT)
#undef WDOT
    gsb[tid] = (a0 + a1) + (a2 + a3);
    LDS_FENCE();
    if (tid < 128) {
      const float ig = gsb[tid], fg = gsb[tid + 128], gg = gsb[tid + 256], og = gsb[tid + 384];
      const float si = __builtin_amdgcn_rcpf(1.f + __expf(-ig));
      const float sf = __builtin_amdgcn_rcpf(1.f + __expf(-fg));
      const float so = __builtin_amdgcn_rcpf(1.f + __expf(-og));
      const float tg = 1.f - 2.f * __builtin_amdgcn_rcpf(1.f + __expf(2.f * gg));
      c = sf * c + si * tg;
      const float tc = 1.f - 2.f * __builtin_amdgcn_rcpf(1.f + __expf(2.f * c));
      const float h = so * tc;
      hbuf[tid] = (f16)h;
      outp[((long)b * 512 + t) * 256 + dir * 128 + tid] = (bf16)h;
    }
    LDS_FENCE();
    xv = xnext;
  }
}

// ---------------- final: +bias, *visibility ----------------
__global__ __launch_bounds__(256) void finalize_k(
    const float* __restrict__ y, const float* __restrict__ b2,
    const float* __restrict__ vis, float* __restrict__ out)
{
  const int idx = blockIdx.x * 256 + threadIdx.x;
  if (idx >= NBT * 63) return;
  const int c = idx % 63; const int bt = idx / 63;
  out[idx] = (y[(long)bt * 128 + c] + b2[c]) * vis[bt * 21 + (c / 3)];
}

extern "C" void kernel_launch(void* const* d_in, const int* in_sizes, int n_in,
                              void* d_out, int out_size, void* d_ws, size_t ws_size,
                              hipStream_t stream) {
  (void)in_sizes; (void)n_in;
  const float* feats[2] = { (const float*)d_in[0], (const float*)d_in[1] };
  const float* adj  = (const float*)d_in[2];
  const float* vis  = (const float*)d_in[3];
  const float* gW[2] = { (const float*)d_in[4], (const float*)d_in[6] };
  const float* ga[2] = { (const float*)d_in[5], (const float*)d_in[7] };
  const float* cw_[2] = { (const float*)d_in[8],  (const float*)d_in[10] };
  const float* cb_[2] = { (const float*)d_in[9],  (const float*)d_in[11] };
  const float* bng[2] = { (const float*)d_in[12], (const float*)d_in[16] };
  const float* bnb[2] = { (const float*)d_in[13], (const float*)d_in[17] };
  const float* bnm[2] = { (const float*)d_in[14], (const float*)d_in[18] };
  const float* bnv[2] = { (const float*)d_in[15], (const float*)d_in[19] };
  const float* wq = (const float*)d_in[20], *wk = (const float*)d_in[21];
  const float* wv = (const float*)d_in[22], *wo = (const float*)d_in[23];
  const float* bq = (const float*)d_in[24], *bk = (const float*)d_in[25];
  const float* bv = (const float*)d_in[26], *bo = (const float*)d_in[27];
  const float* Lwih[2][2] = { { (const float*)d_in[28], (const float*)d_in[32] },
                              { (const float*)d_in[36], (const float*)d_in[40] } };
  const float* Lwhh[2][2] = { { (const float*)d_in[29], (const float*)d_in[33] },
                              { (const float*)d_in[37], (const float*)d_in[41] } };
  const float* Lbih[2][2] = { { (const float*)d_in[30], (const float*)d_in[34] },
                              { (const float*)d_in[38], (const float*)d_in[42] } };
  const float* Lbhh[2][2] = { { (const float*)d_in[31], (const float*)d_in[35] },
                              { (const float*)d_in[39], (const float*)d_in[43] } };
  const float* o1w = (const float*)d_in[44], *o1b = (const float*)d_in[45];
  const float* o2w = (const float*)d_in[46], *o2b = (const float*)d_in[47];

  char* base = (char*)d_ws;
  size_t off = 0;
  auto alloc = [&](size_t b) { size_t r = off; off += (b + 1023) & ~(size_t)1023; return r; };
  const size_t SZ_LF  = (size_t)NLF * DD * 2;     // 44.04 MB
  const size_t SZ_CNV = (size_t)CROWS * DD * 2;   // 44.30 MB
  const size_t SZ_BT  = (size_t)NBT * DD * 2;     // 2.10 MB
  const size_t o_w1t = alloc((size_t)256 * 512 * 2);
  const size_t o_w2t = alloc((size_t)256 * 256 * 2);
  const size_t o_cw1 = alloc((size_t)256 * 768 * 2);
  const size_t o_cw2 = alloc((size_t)256 * 768 * 2);
  const size_t o_wq  = alloc((size_t)256 * 256 * 2);
  const size_t o_wk  = alloc((size_t)256 * 256 * 2);
  const size_t o_wv  = alloc((size_t)256 * 256 * 2);
  const size_t o_wo  = alloc((size_t)256 * 256 * 2);
  const size_t o_o1w = alloc((size_t)256 * 256 * 2);
  const size_t o_o2p = alloc((size_t)128 * 256 * 2);
  const size_t o_lw0 = alloc((size_t)512 * 256 * 2);
  const size_t o_lw1 = alloc((size_t)512 * 256 * 2);
  const size_t o_lw2 = alloc((size_t)512 * 256 * 2);
  const size_t o_lw3 = alloc((size_t)512 * 256 * 2);
  const size_t o_ss  = alloc((size_t)4 * 256 * 4);
  const size_t o_B1  = alloc(SZ_LF);
  const size_t o_B2  = alloc(SZ_CNV);
  const size_t o_B3  = alloc(SZ_CNV);
  const size_t o_lfL = alloc(SZ_LF);
  const size_t o_lfR = alloc(SZ_LF);
  const size_t o_le  = alloc(SZ_BT);
  const size_t o_re  = alloc(SZ_BT);
  const size_t o_h1L = alloc(SZ_BT);
  const size_t o_h1R = alloc(SZ_BT);
  const size_t o_hoL = alloc(SZ_BT);
  const size_t o_hoR = alloc(SZ_BT);
  const size_t o_t1  = alloc(SZ_BT);
  const size_t o_y32 = alloc((size_t)NBT * 128 * 4);
  const size_t NEED = off;
  if (ws_size < NEED) {   // graceful diagnostic: zero output, clean absmax-fail
    zero_out<<<(out_size + 255) / 256, 256, 0, stream>>>((float*)d_out, out_size);
    return;
  }
  auto P = [&](size_t o_) { return (void*)(base + o_); };

  auto gemm = [&](const void* A, const void* Bt, void* c32, void* co,
                  const void* bias_, const void* sc_, const void* sh_,
                  long M, int N, int K, int lda, int flags) {
    dim3 g((unsigned)(N / 128), (unsigned)((M + 127) / 128));
    gemm_bf16<<<g, 256, 0, stream>>>(A, (const bf16*)Bt, (float*)c32, (bf16*)co,
                                     (const float*)bias_, (const float*)sc_,
                                     (const float*)sh_, (int)M, N, K, lda, flags);
  };
  auto cvt = [&](const float* s, void* d, long n) {
    cvt_k<<<(unsigned)((n + 255) / 256), 256, 0, stream>>>(s, (bf16*)d, n);
  };

  // ---- weight prep ----
  prep_gatW<<<512, 256, 0, stream>>>(gW[0], (bf16*)P(o_w1t), 512);
  prep_gatW<<<256, 256, 0, stream>>>(gW[1], (bf16*)P(o_w2t), 256);
  prep_convw<<<768, 256, 0, stream>>>(cw_[0], (bf16*)P(o_cw1));
  prep_convw<<<768, 256, 0, stream>>>(cw_[1], (bf16*)P(o_cw2));
  cvt(wq, P(o_wq), 65536); cvt(wk, P(o_wk), 65536);
  cvt(wv, P(o_wv), 65536); cvt(wo, P(o_wo), 65536);
  cvt(o1w, P(o_o1w), 65536);
  cvt(Lwih[0][0], P(o_lw0), 131072); cvt(Lwih[0][1], P(o_lw1), 131072);
  cvt(Lwih[1][0], P(o_lw2), 131072); cvt(Lwih[1][1], P(o_lw3), 131072);
  prep_out2<<<128, 256, 0, stream>>>(o2w, (bf16*)P(o_o2p));
  float* sc1 = (float*)P(o_ss); float* sh1 = sc1 + 256;
  float* sc2 = sh1 + 256;       float* sh2 = sc2 + 256;
  prep_scsh<<<1, 256, 0, stream>>>(cb_[0], bng[0], bnb[0], bnm[0], bnv[0], sc1, sh1);
  prep_scsh<<<1, 256, 0, stream>>>(cb_[1], bng[1], bnb[1], bnm[1], bnv[1], sc2, sh2);

  bf16* B1 = (bf16*)P(o_B1);
  bf16* B2 = (bf16*)P(o_B2);   // guard row at row 0; conv space = B2+DD
  bf16* B3 = (bf16*)P(o_B3);
  bf16* lfb[2] = { (bf16*)P(o_lfL), (bf16*)P(o_lfR) };

  // ---- per-hand: GAT x2 -> conv x2 -> lf ----
  for (int hd = 0; hd < 2; hd++) {
    gemm(feats[hd], P(o_w1t), nullptr, B1, nullptr, nullptr, nullptr,
         NLF, 256, 512, 512, 1);                                   // A_F32
    gat_attn<<<NBT, 256, 0, stream>>>(B1, ga[0], adj, B1, 0);      // in-place
    gemm(B1, P(o_w2t), nullptr, B2, nullptr, nullptr, nullptr,
         NLF, 256, 256, 256, 0);
    pad_zero<<<336, 256, 0, stream>>>(B3 + DD);
    gat_attn<<<NBT, 256, 0, stream>>>(B2, ga[1], adj, B3 + DD, 1); // conv layout
    // conv1: single GEMM K=768 over 3 contiguous rows, fused BN+ReLU+padzero
    gemm(B3, P(o_cw1), nullptr, B2 + DD, nullptr, sc1, sh1,
         CONV_M, 256, 768, 256, 8 | 4 | 16);
    // conv2: fused BN+ReLU, write straight to lf layout
    gemm(B2, P(o_cw2), nullptr, lfb[hd], nullptr, sc2, sh2,
         CONV_M, 256, 768, 256, 8 | 4 | 32);
  }

  // ---- cross-hand MHA ----
  // pass1 a_l2r: q=lf_L, k/v=lf_R
  gemm(lfb[0], P(o_wq), nullptr, B1, bq, nullptr, nullptr, NLF, 256, 256, 256, 0);
  gemm(lfb[1], P(o_wk), nullptr, B2, bk, nullptr, nullptr, NLF, 256, 256, 256, 0);
  gemm(lfb[1], P(o_wv), nullptr, B3, bv, nullptr, nullptr, NLF, 256, 256, 256, 0);
  mha_core<<<NBT, 256, 0, stream>>>(B1, B2, B3, B1);               // O in-place
  gemm(B1, P(o_wo), nullptr, B2, bo, nullptr, nullptr, NLF, 256, 256, 256, 0);
  pool_kernel<<<NBT, 256, 0, stream>>>(lfb[1], B2, (bf16*)P(o_re)); // re = rf+0.5*a_l2r
  // pass2 a_r2l: q=lf_R, k/v=lf_L
  gemm(lfb[1], P(o_wq), nullptr, B1, bq, nullptr, nullptr, NLF, 256, 256, 256, 0);
  gemm(lfb[0], P(o_wk), nullptr, B3, bk, nullptr, nullptr, NLF, 256, 256, 256, 0);
  gemm(lfb[0], P(o_wv), nullptr, B2, bv, nullptr, nullptr, NLF, 256, 256, 256, 0);
  mha_core<<<NBT, 256, 0, stream>>>(B1, B3, B2, B1);
  gemm(B1, P(o_wo), nullptr, B3, bo, nullptr, nullptr, NLF, 256, 256, 256, 0);
  pool_kernel<<<NBT, 256, 0, stream>>>(lfb[0], B3, (bf16*)P(o_le)); // le = lf+0.5*a_r2l

  // ---- BiLSTM (xw aliases B2 region: 33.5 MB f32) ----
  float* xw = (float*)P(o_B2);
  auto xslot = [&](int h_, int d_) { return (void*)(xw + ((size_t)(h_ * 2 + d_)) * NBT * 512); };
  gemm(P(o_le), P(o_lw0), xslot(0, 0), nullptr, nullptr, nullptr, nullptr, NBT, 512, 256, 256, 2);
  gemm(P(o_le), P(o_lw1), xslot(0, 1), nullptr, nullptr, nullptr, nullptr, NBT, 512, 256, 256, 2);
  gemm(P(o_re), P(o_lw0), xslot(1, 0), nullptr, nullptr, nullptr, nullptr, NBT, 512, 256, 256, 2);
  gemm(P(o_re), P(o_lw1), xslot(1, 1), nullptr, nullptr, nullptr, nullptr, NBT, 512, 256, 256, 2);
  lstm_lds<<<32, 512, 0, stream>>>(xw, Lwhh[0][0], Lwhh[0][1],
      Lbih[0][0], Lbhh[0][0], Lbih[0][1], Lbhh[0][1],
      (bf16*)P(o_h1L), (bf16*)P(o_h1R));
  gemm(P(o_h1L), P(o_lw2), xslot(0, 0), nullptr, nullptr, nullptr, nullptr, NBT, 512, 256, 256, 2);
  gemm(P(o_h1L), P(o_lw3), xslot(0, 1), nullptr, nullptr, nullptr, nullptr, NBT, 512, 256, 256, 2);
  gemm(P(o_h1R), P(o_lw2), xslot(1, 0), nullptr, nullptr, nullptr, nullptr, NBT, 512, 256, 256, 2);
  gemm(P(o_h1R), P(o_lw3), xslot(1, 1), nullptr, nullptr, nullptr, nullptr, NBT, 512, 256, 256, 2);
  lstm_lds<<<32, 512, 0, stream>>>(xw, Lwhh[1][0], Lwhh[1][1],
      Lbih[1][0], Lbhh[1][0], Lbih[1][1], Lbhh[1][1],
      (bf16*)P(o_hoL), (bf16*)P(o_hoR));

  // ---- heads + visibility ----
  for (int hd = 0; hd < 2; hd++) {
    const void* hin = hd ? P(o_hoR) : P(o_hoL);
    gemm(hin, P(o_o1w), nullptr, P(o_t1), o1b, nullptr, nullptr, NBT, 256, 256, 256, 4);
    gemm(P(o_t1), P(o_o2p), P(o_y32), nullptr, nullptr, nullptr, nullptr, NBT, 128, 256, 256, 2);
    finalize_k<<<(NBT * 63 + 255) / 256, 256, 0, stream>>>(
        (const float*)P(o_y32), o2b, vis, (float*)d_out + (size_t)hd * NBT * 63);
  }
}

// Round 10
// 2337.267 us; speedup vs baseline: 1.5384x; 1.0375x over previous
//
#include <hip/hip_runtime.h>

typedef __bf16 bf16;
typedef bf16 bf16x8 __attribute__((ext_vector_type(8)));
typedef float f32x4 __attribute__((ext_vector_type(4)));
typedef _Float16 f16;
typedef f16 f16x8 __attribute__((ext_vector_type(8)));

#define NBT 4096      // B*T = 8*512
#define NJ 21
#define NLF 86016     // NBT*NJ
#define DD 256
#define CONV_M 86352  // 168*514
#define SPAD 514
#define CROWS 86528   // 1 guard row + 86352 + overrun slack

// async global->LDS, 16B per lane; LDS dest is WAVE-UNIFORM base + lane*16
__device__ __forceinline__ void gload16(const bf16* g, bf16* l) {
  __builtin_amdgcn_global_load_lds(
      (const __attribute__((address_space(1))) unsigned int*)g,
      (__attribute__((address_space(3))) unsigned int*)l, 16, 0, 0);
}

// flags: 1=A_F32  2=OUT_F32(C32)  4=RELU  8=BNSS(sc/sh)  16=PADZ(conv layout)
//        32=LFOUT(remap conv row -> lf row)  bias!=null => +bias
__global__ __launch_bounds__(256, 2) void gemm_bf16(
    const void* __restrict__ Av, const bf16* __restrict__ Bt,
    float* __restrict__ C32, bf16* __restrict__ Cout,
    const float* __restrict__ bias, const float* __restrict__ sc,
    const float* __restrict__ sh, int M, int N, int K, int lda, int flags)
{
  __shared__ __align__(16) bf16 As[128][32];   // linear: gload_lds dest
  __shared__ __align__(16) bf16 Bs[128][32];
  const int tid = threadIdx.x;
  const long m0 = (long)blockIdx.y * 128;
  const int n0 = blockIdx.x * 128;
  const int wave = tid >> 6, lane = tid & 63;
  const int wm = (wave & 1) * 64, wn = (wave >> 1) * 64;
  const int frow = lane & 15, fkb = (lane >> 4) * 8;
  const int crow = lane >> 2, ccol = (lane & 3) * 8;  // gload lane->elem map
  f32x4 acc[4][4] = {};
  for (int k0 = 0; k0 < K; k0 += 32) {
    if (flags & 1) {   // f32 A: VALU convert-stage (GAT1 only)
      const int lr = tid >> 1, lc = (tid & 1) * 16;
      const float* ap = (const float*)Av + (m0 + lr) * (long)lda + (k0 + lc);
      bf16x8 t0, t1;
      #pragma unroll
      for (int u = 0; u < 8; u++) { t0[u] = (bf16)ap[u]; t1[u] = (bf16)ap[8 + u]; }
      *(bf16x8*)(&As[lr][lc])     = t0;
      *(bf16x8*)(&As[lr][lc + 8]) = t1;
    } else {           // async A: wave w stages 1KB chunks 2w, 2w+1
      #pragma unroll
      for (int cc = 0; cc < 2; cc++) {
        const int ch = wave * 2 + cc;
        gload16((const bf16*)Av + (m0 + ch * 16 + crow) * (long)lda + (k0 + ccol),
                &As[ch * 16][0]);
      }
    }
    #pragma unroll
    for (int cc = 0; cc < 2; cc++) {   // async B
      const int ch = wave * 2 + cc;
      gload16(Bt + (n0 + ch * 16 + crow) * (long)K + (k0 + ccol),
              &Bs[ch * 16][0]);
    }
    __syncthreads();   // drains vmcnt (gload) + lgkm (VALU stores)
    bf16x8 af[4], bg[4];
    #pragma unroll
    for (int i = 0; i < 4; i++) af[i] = *(const bf16x8*)(&As[wm + i * 16 + frow][fkb]);
    #pragma unroll
    for (int j = 0; j < 4; j++) bg[j] = *(const bf16x8*)(&Bs[wn + j * 16 + frow][fkb]);
    #pragma unroll
    for (int i = 0; i < 4; i++)
      #pragma unroll
      for (int j = 0; j < 4; j++)
        acc[i][j] = __builtin_amdgcn_mfma_f32_16x16x32_bf16(af[i], bg[j], acc[i][j], 0, 0, 0);
    __syncthreads();
  }
  const int col = lane & 15, rbase = (lane >> 4) * 4;
  #pragma unroll
  for (int i = 0; i < 4; i++) {
    #pragma unroll
    for (int j = 0; j < 4; j++) {
      const int nn = n0 + wn + j * 16 + col;
      #pragma unroll
      for (int r = 0; r < 4; r++) {
        const long mm = m0 + wm + i * 16 + rbase + r;
        if (mm >= M) continue;
        float v = acc[i][j][r];
        if (flags & 2) { C32[mm * (long)N + nn] = v; continue; }
        if (flags & 8) v = v * sc[nn] + sh[nn];
        else if (bias) v += bias[nn];
        if (flags & 4) v = fmaxf(v, 0.f);
        if (flags & 16) {
          const int s = (int)(mm % SPAD);
          if (s == 0 || s == SPAD - 1) v = 0.f;
          Cout[mm * (long)N + nn] = (bf16)v;
        } else if (flags & 32) {
          const long hj = mm / SPAD; const int s = (int)(mm - hj * SPAD);
          if (s == 0 || s == SPAD - 1) continue;
          const long b = hj / NJ; const int j2 = (int)(hj - b * NJ);
          const long dst = (b * 512 + (s - 1)) * NJ + j2;
          Cout[dst * (long)N + nn] = (bf16)v;
        } else {
          Cout[mm * (long)N + nn] = (bf16)v;
        }
      }
    }
  }
}

// ---------------- weight prep (f32 -> bf16) ----------------
__global__ void cvt_k(const float* __restrict__ s, bf16* __restrict__ d, long n) {
  long i = (long)blockIdx.x * 256 + threadIdx.x;
  if (i < n) d[i] = (bf16)s[i];
}
__global__ void prep_gatW(const float* __restrict__ W, bf16* __restrict__ Wt, int F) {
  long idx = (long)blockIdx.x * 256 + threadIdx.x;   // 256*F
  if (idx >= 256L * F) return;
  int n = (int)(idx / F), f = (int)(idx % F);
  Wt[idx] = (bf16)W[((long)(n >> 6) * F + f) * 64 + (n & 63)];
}
__global__ void prep_convw(const float* __restrict__ w, bf16* __restrict__ wp) {
  int idx = blockIdx.x * 256 + threadIdx.x;          // 256*768
  int n = idx / 768, k = idx % 768, tap = k >> 8, i = k & 255;
  wp[idx] = (bf16)w[(n * 256 + i) * 3 + tap];
}
__global__ void prep_out2(const float* __restrict__ w, bf16* __restrict__ wp) {
  int idx = blockIdx.x * 256 + threadIdx.x;          // 128*256
  wp[idx] = (idx < 63 * 256) ? (bf16)w[idx] : (bf16)0.f;
}
__global__ void prep_scsh(const float* __restrict__ cb, const float* __restrict__ g,
                          const float* __restrict__ be, const float* __restrict__ m,
                          const float* __restrict__ v, float* __restrict__ sc,
                          float* __restrict__ sh) {
  int c = threadIdx.x;
  float rs = rsqrtf(v[c] + 1e-5f) * g[c];
  sc[c] = rs; sh[c] = (cb[c] - m[c]) * rs + be[c];
}
__global__ void pad_zero(bf16* __restrict__ convIn) {
  int idx = blockIdx.x * 256 + threadIdx.x;          // 168*2*256
  int hj = idx >> 9, s = ((idx >> 8) & 1) ? (SPAD - 1) : 0, c = idx & 255;
  convIn[((long)hj * SPAD + s) * DD + c] = (bf16)0.f;
}
__global__ void zero_out(float* __restrict__ o, long n) {
  long i = (long)blockIdx.x * 256 + threadIdx.x;
  if (i < n) o[i] = 0.f;
}

// ---------------- GAT attention (per bt block; in-place safe) ----------------
__global__ __launch_bounds__(256) void gat_attn(
    const bf16* __restrict__ Wh, const float* __restrict__ a,
    const float* __restrict__ adj, bf16* __restrict__ out, int convMode)
{
  const int bt = blockIdx.x, tid = threadIdx.x;
  __shared__ float whs[NJ][DD];
  __shared__ float s1[4][NJ], s2[4][NJ];
  __shared__ float att[4][NJ][NJ];
  const long base = (long)bt * NJ * DD;
  for (int i = tid; i < NJ * DD; i += 256)
    whs[i >> 8][i & 255] = (float)Wh[base + i];
  __syncthreads();
  if (tid < 4 * NJ) {
    const int h = tid / NJ, i = tid % NJ;
    float x1 = 0.f, x2 = 0.f;
    for (int d = 0; d < 64; d++) {
      const float w = whs[i][h * 64 + d];
      x1 += w * a[h * 128 + d];
      x2 += w * a[h * 128 + 64 + d];
    }
    s1[h][i] = x1; s2[h][i] = x2;
  }
  __syncthreads();
  for (int idx = tid; idx < 4 * NJ * NJ; idx += 256) {
    const int h = idx / (NJ * NJ), r = idx % (NJ * NJ), i = r / NJ, j = r % NJ;
    float e = s1[h][i] + s2[h][j];
    e = e > 0.f ? e : 0.2f * e;
    att[h][i][j] = (adj[i * NJ + j] > 0.f) ? e : -9e15f;
  }
  __syncthreads();
  if (tid < 4 * NJ) {
    const int h = tid / NJ, i = tid % NJ;
    float mx = -3e38f;
    for (int j = 0; j < NJ; j++) mx = fmaxf(mx, att[h][i][j]);
    float sum = 0.f;
    for (int j = 0; j < NJ; j++) { const float ex = __expf(att[h][i][j] - mx); att[h][i][j] = ex; sum += ex; }
    const float inv = 1.f / sum;
    for (int j = 0; j < NJ; j++) att[h][i][j] *= inv;
  }
  __syncthreads();
  const int b = bt >> 9, t = bt & 511;
  for (int idx = tid; idx < NJ * DD; idx += 256) {
    const int i = idx >> 8, c = idx & 255, h = c >> 6;
    float s = 0.f;
    for (int j = 0; j < NJ; j++) s += att[h][i][j] * whs[j][c];
    s = s > 0.f ? s : (__expf(s) - 1.f);              // ELU
    const long row = convMode ? (((long)(b * NJ + i)) * SPAD + (t + 1)) : ((long)bt * NJ + i);
    out[row * DD + c] = (bf16)s;
  }
}

// ---------------- MHA core (per bt block; O may alias Q) ----------------
__global__ __launch_bounds__(256) void mha_core(
    const bf16* __restrict__ Q, const bf16* __restrict__ K,
    const bf16* __restrict__ V, bf16* __restrict__ O)
{
  const int bt = blockIdx.x, tid = threadIdx.x;
  __shared__ bf16 qs[NJ][DD], ks[NJ][DD], vs[NJ][DD];
  __shared__ float att[4][NJ][NJ];
  const long base = (long)bt * NJ * DD;
  for (int i = tid; i < NJ * DD; i += 256) {
    const int r = i >> 8, c = i & 255;
    qs[r][c] = Q[base + i]; ks[r][c] = K[base + i]; vs[r][c] = V[base + i];
  }
  __syncthreads();
  for (int idx = tid; idx < 4 * NJ * NJ; idx += 256) {
    const int h = idx / (NJ * NJ), r = idx % (NJ * NJ), i = r / NJ, j = r % NJ;
    float s = 0.f;
    for (int d = 0; d < 64; d++) s += (float)qs[i][h * 64 + d] * (float)ks[j][h * 64 + d];
    att[h][i][j] = s * 0.125f;
  }
  __syncthreads();
  if (tid < 4 * NJ) {
    const int h = tid / NJ, i = tid % NJ;
    float mx = -3e38f;
    for (int j = 0; j < NJ; j++) mx = fmaxf(mx, att[h][i][j]);
    float sum = 0.f;
    for (int j = 0; j < NJ; j++) { const float ex = __expf(att[h][i][j] - mx); att[h][i][j] = ex; sum += ex; }
    const float inv = 1.f / sum;
    for (int j = 0; j < NJ; j++) att[h][i][j] *= inv;
  }
  __syncthreads();
  for (int idx = tid; idx < NJ * DD; idx += 256) {
    const int i = idx >> 8, c = idx & 255, h = c >> 6;
    float s = 0.f;
    for (int j = 0; j < NJ; j++) s += att[h][i][j] * (float)vs[j][c];
    O[base + i * DD + c] = (bf16)s;
  }
}

// ---------------- residual + joint-mean pool ----------------
__global__ __launch_bounds__(256) void pool_kernel(
    const bf16* __restrict__ lf, const bf16* __restrict__ ao, bf16* __restrict__ o)
{
  const int bt = blockIdx.x, c = threadIdx.x;
  float s = 0.f;
  for (int j = 0; j < NJ; j++) {
    const long r = ((long)bt * NJ + j) * DD + c;
    s += (float)lf[r] + 0.5f * (float)ao[r];
  }
  o[(long)bt * DD + c] = (bf16)(s * (1.f / 21.f));
}

// ---------------- persistent LSTM: weights in LDS (R9 state, unchanged) ----
// R9: 321us/dispatch. Weight re-read from LDS each step = LDS-BW floor
// (~1024cyc/step); 5 register-pinning attempts all defeated by the allocator.
#define REP16(X) X(0) X(1) X(2) X(3) X(4) X(5) X(6) X(7) X(8) X(9) X(10) X(11) \
  X(12) X(13) X(14) X(15)

#define LDS_FENCE() do { \
  asm volatile("s_waitcnt lgkmcnt(0)" ::: "memory"); \
  __builtin_amdgcn_sched_barrier(0); \
  __builtin_amdgcn_s_barrier(); \
  __builtin_amdgcn_sched_barrier(0); \
} while (0)

__global__ __launch_bounds__(512, 1) void lstm_lds(
    const float* __restrict__ xw,
    const float* __restrict__ whhF, const float* __restrict__ whhB,
    const float* __restrict__ bihF, const float* __restrict__ bhhF,
    const float* __restrict__ bihB, const float* __restrict__ bhhB,
    bf16* __restrict__ outL, bf16* __restrict__ outR)
{
  const int wg = blockIdx.x;
  const int hand = wg >> 4, dir = (wg >> 3) & 1, b = wg & 7;
  const int tid = threadIdx.x;
  const float* whh = dir ? whhB : whhF;

  __shared__ f16 whhs[512][136];   // 139,264 B -> 1 WG/CU
  __shared__ f16 hbuf[136];
  __shared__ float gsb[512];

  for (int i = tid; i < 512 * 128; i += 512)        // coalesced f32 -> f16 LDS
    whhs[i >> 7][i & 127] = (f16)whh[i];
  if (tid < 136) hbuf[tid] = (f16)0.f;
  const float bias = (dir ? bihB : bihF)[tid] + (dir ? bhhB : bhhF)[tid];
  float c = 0.f;
  const float* xp = xw + (((long)(hand * 2 + dir)) * NBT + (long)b * 512) * 512;
  bf16* outp = hand ? outR : outL;
  float xv = xp[(long)(dir ? 511 : 0) * 512 + tid];  // prefetch step 0
  __syncthreads();

  const f16* wrow = &whhs[tid][0];
#define WRD(i) f16x8 w##i = *(const f16x8*)(wrow + (i) * 8);
  REP16(WRD)
#undef WRD

  for (int s = 0; s < 512; s++) {
    const int t = dir ? (511 - s) : s;
    const int tn = dir ? (510 - s) : (s + 1);
    float xnext = 0.f;
    if (s < 511) xnext = xp[(long)tn * 512 + tid];   // prefetch next step
    float a0 = xv + bias, a1 = 0.f, a2 = 0.f, a3 = 0.f;
#define WDOT(i) { \
    const f16x8 hv = *(const f16x8*)(&hbuf[(i) * 8]); \
    a0 = __builtin_amdgcn_fdot2(__builtin_shufflevector(w##i, w##i, 0, 1), \
                                __builtin_shufflevector(hv, hv, 0, 1), a0, false); \
    a1 = __builtin_amdgcn_fdot2(__builtin_shufflevector(w##i, w##i, 2, 3), \
                                __builtin_shufflevector(hv, hv, 2, 3), a1, false); \
    a2 = __builtin_amdgcn_fdot2(__builtin_shufflevector(w##i, w##i, 4, 5), \
                                __builtin_shufflevector(hv, hv, 4, 5), a2, false); \
    a3 = __builtin_amdgcn_fdot2(__builtin_shufflevector(w##i, w##i, 6, 7), \
                                __builtin_shufflevector(hv, hv, 6, 7), a3, false); }
    REP16(WDOT)
#undef WDOT
    gsb[tid] = (a0 + a1) + (a2 + a3);
    LDS_FENCE();
    if (tid < 128) {
      const float ig = gsb[tid], fg = gsb[tid + 128], gg = gsb[tid + 256], og = gsb[tid + 384];
      const float si = __builtin_amdgcn_rcpf(1.f + __expf(-ig));
      const float sf = __builtin_amdgcn_rcpf(1.f + __expf(-fg));
      const float so = __builtin_amdgcn_rcpf(1.f + __expf(-og));
      const float tg = 1.f - 2.f * __builtin_amdgcn_rcpf(1.f + __expf(2.f * gg));
      c = sf * c + si * tg;
      const float tc = 1.f - 2.f * __builtin_amdgcn_rcpf(1.f + __expf(2.f * c));
      const float h = so * tc;
      hbuf[tid] = (f16)h;
      outp[((long)b * 512 + t) * 256 + dir * 128 + tid] = (bf16)h;
    }
    LDS_FENCE();
    xv = xnext;
  }
}

// ---------------- final: +bias, *visibility ----------------
__global__ __launch_bounds__(256) void finalize_k(
    const float* __restrict__ y, const float* __restrict__ b2,
    const float* __restrict__ vis, float* __restrict__ out)
{
  const int idx = blockIdx.x * 256 + threadIdx.x;
  if (idx >= NBT * 63) return;
  const int c = idx % 63; const int bt = idx / 63;
  out[idx] = (y[(long)bt * 128 + c] + b2[c]) * vis[bt * 21 + (c / 3)];
}

extern "C" void kernel_launch(void* const* d_in, const int* in_sizes, int n_in,
                              void* d_out, int out_size, void* d_ws, size_t ws_size,
                              hipStream_t stream) {
  (void)in_sizes; (void)n_in;
  const float* feats[2] = { (const float*)d_in[0], (const float*)d_in[1] };
  const float* adj  = (const float*)d_in[2];
  const float* vis  = (const float*)d_in[3];
  const float* gW[2] = { (const float*)d_in[4], (const float*)d_in[6] };
  const float* ga[2] = { (const float*)d_in[5], (const float*)d_in[7] };
  const float* cw_[2] = { (const float*)d_in[8],  (const float*)d_in[10] };
  const float* cb_[2] = { (const float*)d_in[9],  (const float*)d_in[11] };
  const float* bng[2] = { (const float*)d_in[12], (const float*)d_in[16] };
  const float* bnb[2] = { (const float*)d_in[13], (const float*)d_in[17] };
  const float* bnm[2] = { (const float*)d_in[14], (const float*)d_in[18] };
  const float* bnv[2] = { (const float*)d_in[15], (const float*)d_in[19] };
  const float* wq = (const float*)d_in[20], *wk = (const float*)d_in[21];
  const float* wv = (const float*)d_in[22], *wo = (const float*)d_in[23];
  const float* bq = (const float*)d_in[24], *bk = (const float*)d_in[25];
  const float* bv = (const float*)d_in[26], *bo = (const float*)d_in[27];
  const float* Lwih[2][2] = { { (const float*)d_in[28], (const float*)d_in[32] },
                              { (const float*)d_in[36], (const float*)d_in[40] } };
  const float* Lwhh[2][2] = { { (const float*)d_in[29], (const float*)d_in[33] },
                              { (const float*)d_in[37], (const float*)d_in[41] } };
  const float* Lbih[2][2] = { { (const float*)d_in[30], (const float*)d_in[34] },
                              { (const float*)d_in[38], (const float*)d_in[42] } };
  const float* Lbhh[2][2] = { { (const float*)d_in[31], (const float*)d_in[35] },
                              { (const float*)d_in[39], (const float*)d_in[43] } };
  const float* o1w = (const float*)d_in[44], *o1b = (const float*)d_in[45];
  const float* o2w = (const float*)d_in[46], *o2b = (const float*)d_in[47];

  char* base = (char*)d_ws;
  size_t off = 0;
  auto alloc = [&](size_t b) { size_t r = off; off += (b + 1023) & ~(size_t)1023; return r; };
  const size_t SZ_LF  = (size_t)NLF * DD * 2;     // 44.04 MB
  const size_t SZ_CNV = (size_t)CROWS * DD * 2;   // 44.30 MB
  const size_t SZ_BT  = (size_t)NBT * DD * 2;     // 2.10 MB
  const size_t o_w1t = alloc((size_t)256 * 512 * 2);
  const size_t o_w2t = alloc((size_t)256 * 256 * 2);
  const size_t o_cw1 = alloc((size_t)256 * 768 * 2);
  const size_t o_cw2 = alloc((size_t)256 * 768 * 2);
  const size_t o_wq  = alloc((size_t)256 * 256 * 2);
  const size_t o_wk  = alloc((size_t)256 * 256 * 2);
  const size_t o_wv  = alloc((size_t)256 * 256 * 2);
  const size_t o_wo  = alloc((size_t)256 * 256 * 2);
  const size_t o_o1w = alloc((size_t)256 * 256 * 2);
  const size_t o_o2p = alloc((size_t)128 * 256 * 2);
  const size_t o_lw0 = alloc((size_t)512 * 256 * 2);
  const size_t o_lw1 = alloc((size_t)512 * 256 * 2);
  const size_t o_lw2 = alloc((size_t)512 * 256 * 2);
  const size_t o_lw3 = alloc((size_t)512 * 256 * 2);
  const size_t o_ss  = alloc((size_t)4 * 256 * 4);
  const size_t o_B1  = alloc(SZ_LF);
  const size_t o_B2  = alloc(SZ_CNV);
  const size_t o_B3  = alloc(SZ_CNV);
  const size_t o_lfL = alloc(SZ_LF);
  const size_t o_lfR = alloc(SZ_LF);
  const size_t o_le  = alloc(SZ_BT);
  const size_t o_re  = alloc(SZ_BT);
  const size_t o_h1L = alloc(SZ_BT);
  const size_t o_h1R = alloc(SZ_BT);
  const size_t o_hoL = alloc(SZ_BT);
  const size_t o_hoR = alloc(SZ_BT);
  const size_t o_t1  = alloc(SZ_BT);
  const size_t o_y32 = alloc((size_t)NBT * 128 * 4);
  const size_t NEED = off;
  if (ws_size < NEED) {   // graceful diagnostic: zero output, clean absmax-fail
    zero_out<<<(out_size + 255) / 256, 256, 0, stream>>>((float*)d_out, out_size);
    return;
  }
  auto P = [&](size_t o_) { return (void*)(base + o_); };

  auto gemm = [&](const void* A, const void* Bt, void* c32, void* co,
                  const void* bias_, const void* sc_, const void* sh_,
                  long M, int N, int K, int lda, int flags) {
    dim3 g((unsigned)(N / 128), (unsigned)((M + 127) / 128));
    gemm_bf16<<<g, 256, 0, stream>>>(A, (const bf16*)Bt, (float*)c32, (bf16*)co,
                                     (const float*)bias_, (const float*)sc_,
                                     (const float*)sh_, (int)M, N, K, lda, flags);
  };
  auto cvt = [&](const float* s, void* d, long n) {
    cvt_k<<<(unsigned)((n + 255) / 256), 256, 0, stream>>>(s, (bf16*)d, n);
  };

  // ---- weight prep ----
  prep_gatW<<<512, 256, 0, stream>>>(gW[0], (bf16*)P(o_w1t), 512);
  prep_gatW<<<256, 256, 0, stream>>>(gW[1], (bf16*)P(o_w2t), 256);
  prep_convw<<<768, 256, 0, stream>>>(cw_[0], (bf16*)P(o_cw1));
  prep_convw<<<768, 256, 0, stream>>>(cw_[1], (bf16*)P(o_cw2));
  cvt(wq, P(o_wq), 65536); cvt(wk, P(o_wk), 65536);
  cvt(wv, P(o_wv), 65536); cvt(wo, P(o_wo), 65536);
  cvt(o1w, P(o_o1w), 65536);
  cvt(Lwih[0][0], P(o_lw0), 131072); cvt(Lwih[0][1], P(o_lw1), 131072);
  cvt(Lwih[1][0], P(o_lw2), 131072); cvt(Lwih[1][1], P(o_lw3), 131072);
  prep_out2<<<128, 256, 0, stream>>>(o2w, (bf16*)P(o_o2p));
  float* sc1 = (float*)P(o_ss); float* sh1 = sc1 + 256;
  float* sc2 = sh1 + 256;       float* sh2 = sc2 + 256;
  prep_scsh<<<1, 256, 0, stream>>>(cb_[0], bng[0], bnb[0], bnm[0], bnv[0], sc1, sh1);
  prep_scsh<<<1, 256, 0, stream>>>(cb_[1], bng[1], bnb[1], bnm[1], bnv[1], sc2, sh2);

  bf16* B1 = (bf16*)P(o_B1);
  bf16* B2 = (bf16*)P(o_B2);   // guard row at row 0; conv space = B2+DD
  bf16* B3 = (bf16*)P(o_B3);
  bf16* lfb[2] = { (bf16*)P(o_lfL), (bf16*)P(o_lfR) };

  // ---- per-hand: GAT x2 -> conv x2 -> lf ----
  for (int hd = 0; hd < 2; hd++) {
    gemm(feats[hd], P(o_w1t), nullptr, B1, nullptr, nullptr, nullptr,
         NLF, 256, 512, 512, 1);                                   // A_F32
    gat_attn<<<NBT, 256, 0, stream>>>(B1, ga[0], adj, B1, 0);      // in-place
    gemm(B1, P(o_w2t), nullptr, B2, nullptr, nullptr, nullptr,
         NLF, 256, 256, 256, 0);
    pad_zero<<<336, 256, 0, stream>>>(B3 + DD);
    gat_attn<<<NBT, 256, 0, stream>>>(B2, ga[1], adj, B3 + DD, 1); // conv layout
    // conv1: single GEMM K=768 over 3 contiguous rows, fused BN+ReLU+padzero
    gemm(B3, P(o_cw1), nullptr, B2 + DD, nullptr, sc1, sh1,
         CONV_M, 256, 768, 256, 8 | 4 | 16);
    // conv2: fused BN+ReLU, write straight to lf layout
    gemm(B2, P(o_cw2), nullptr, lfb[hd], nullptr, sc2, sh2,
         CONV_M, 256, 768, 256, 8 | 4 | 32);
  }

  // ---- cross-hand MHA ----
  // pass1 a_l2r: q=lf_L, k/v=lf_R
  gemm(lfb[0], P(o_wq), nullptr, B1, bq, nullptr, nullptr, NLF, 256, 256, 256, 0);
  gemm(lfb[1], P(o_wk), nullptr, B2, bk, nullptr, nullptr, NLF, 256, 256, 256, 0);
  gemm(lfb[1], P(o_wv), nullptr, B3, bv, nullptr, nullptr, NLF, 256, 256, 256, 0);
  mha_core<<<NBT, 256, 0, stream>>>(B1, B2, B3, B1);               // O in-place
  gemm(B1, P(o_wo), nullptr, B2, bo, nullptr, nullptr, NLF, 256, 256, 256, 0);
  pool_kernel<<<NBT, 256, 0, stream>>>(lfb[1], B2, (bf16*)P(o_re)); // re = rf+0.5*a_l2r
  // pass2 a_r2l: q=lf_R, k/v=lf_L
  gemm(lfb[1], P(o_wq), nullptr, B1, bq, nullptr, nullptr, NLF, 256, 256, 256, 0);
  gemm(lfb[0], P(o_wk), nullptr, B3, bk, nullptr, nullptr, NLF, 256, 256, 256, 0);
  gemm(lfb[0], P(o_wv), nullptr, B2, bv, nullptr, nullptr, NLF, 256, 256, 256, 0);
  mha_core<<<NBT, 256, 0, stream>>>(B1, B3, B2, B1);
  gemm(B1, P(o_wo), nullptr, B3, bo, nullptr, nullptr, NLF, 256, 256, 256, 0);
  pool_kernel<<<NBT, 256, 0, stream>>>(lfb[0], B3, (bf16*)P(o_le)); // le = lf+0.5*a_r2l

  // ---- BiLSTM (xw aliases B2 region: 33.5 MB f32) ----
  float* xw = (float*)P(o_B2);
  auto xslot = [&](int h_, int d_) { return (void*)(xw + ((size_t)(h_ * 2 + d_)) * NBT * 512); };
  gemm(P(o_le), P(o_lw0), xslot(0, 0), nullptr, nullptr, nullptr, nullptr, NBT, 512, 256, 256, 2);
  gemm(P(o_le), P(o_lw1), xslot(0, 1), nullptr, nullptr, nullptr, nullptr, NBT, 512, 256, 256, 2);
  gemm(P(o_re), P(o_lw0), xslot(1, 0), nullptr, nullptr, nullptr, nullptr, NBT, 512, 256, 256, 2);
  gemm(P(o_re), P(o_lw1), xslot(1, 1), nullptr, nullptr, nullptr, nullptr, NBT, 512, 256, 256, 2);
  lstm_lds<<<32, 512, 0, stream>>>(xw, Lwhh[0][0], Lwhh[0][1],
      Lbih[0][0], Lbhh[0][0], Lbih[0][1], Lbhh[0][1],
      (bf16*)P(o_h1L), (bf16*)P(o_h1R));
  gemm(P(o_h1L), P(o_lw2), xslot(0, 0), nullptr, nullptr, nullptr, nullptr, NBT, 512, 256, 256, 2);
  gemm(P(o_h1L), P(o_lw3), xslot(0, 1), nullptr, nullptr, nullptr, nullptr, NBT, 512, 256, 256, 2);
  gemm(P(o_h1R), P(o_lw2), xslot(1, 0), nullptr, nullptr, nullptr, nullptr, NBT, 512, 256, 256, 2);
  gemm(P(o_h1R), P(o_lw3), xslot(1, 1), nullptr, nullptr, nullptr, nullptr, NBT, 512, 256, 256, 2);
  lstm_lds<<<32, 512, 0, stream>>>(xw, Lwhh[1][0], Lwhh[1][1],
      Lbih[1][0], Lbhh[1][0], Lbih[1][1], Lbhh[1][1],
      (bf16*)P(o_hoL), (bf16*)P(o_hoR));

  // ---- heads + visibility ----
  for (int hd = 0; hd < 2; hd++) {
    const void* hin = hd ? P(o_hoR) : P(o_hoL);
    gemm(hin, P(o_o1w), nullptr, P(o_t1), o1b, nullptr, nullptr, NBT, 256, 256, 256, 4);
    gemm(P(o_t1), P(o_o2p), P(o_y32), nullptr, nullptr, nullptr, nullptr, NBT, 128, 256, 256, 2);
    finalize_k<<<(NBT * 63 + 255) / 256, 256, 0, stream>>>(
        (const float*)P(o_y32), o2b, vis, (float*)d_out + (size_t)hd * NBT * 63);
  }
}